// Round 13
// baseline (170.318 us; speedup 1.0000x reference)
//
#include <hip/hip_runtime.h>

typedef unsigned short u16;
typedef unsigned int   u32;
typedef unsigned char  u8;
typedef unsigned long long u64;
typedef __attribute__((ext_vector_type(8))) short bf16x8;
typedef __attribute__((ext_vector_type(4))) float f32x4;
typedef __attribute__((ext_vector_type(16))) float f32x16;

// fp32 -> bf16 (round-nearest-even), bit trick
__device__ __forceinline__ u16 f2b(float f) {
  union { float f; u32 u; } v; v.f = f;
  u32 u = v.u;
  return (u16)((u + 0x7fffu + ((u >> 16) & 1u)) >> 16);
}
__device__ __forceinline__ float b2f(u16 x) {
  union { u32 u; float f; } v; v.u = ((u32)x) << 16; return v.f;
}
__device__ __forceinline__ u32 pk2(u16 lo, u16 hi) { return (u32)lo | ((u32)hi << 16); }

// 2^x via v_exp_f32
__device__ __forceinline__ float fexp2(float x) { return __builtin_amdgcn_exp2f(x); }

// pack 2 f32 -> 2 bf16 in one instruction (RNE)
__device__ __forceinline__ u32 cvtpk(float lo, float hi) {
  u32 r;
  asm("v_cvt_pk_bf16_f32 %0, %1, %2" : "=v"(r) : "v"(lo), "v"(hi));
  return r;
}

// v_permlane32_swap_b32: a.hi32lanes <-> b.lo32lanes
__device__ __forceinline__ void swap32(u32& a, u32& b) {
  asm("v_permlane32_swap_b32 %0, %1" : "+v"(a), "+v"(b));
}

// async global->LDS, 16B per lane; LDS dest = wave-uniform base + lane*16
__device__ __forceinline__ void glds16(const u16* g, u16* l) {
  __builtin_amdgcn_global_load_lds((const __attribute__((address_space(1))) void*)g,
                                   (__attribute__((address_space(3))) void*)l, 16, 0, 0);
}

// ---------------------------------------------------------------------------
// Mask dtype detection (parallel): flag[0]!=0 -> bool; else flag[1]!=0 -> f32
// ---------------------------------------------------------------------------
__global__ __launch_bounds__(256) void mask_detect(const u8* __restrict__ raw,
                                                   int* __restrict__ flag) {
  int i = blockIdx.x * 256 + threadIdx.x;
  uint4 x = ((const uint4*)raw)[i];
  u32 o = x.x | x.y | x.z | x.w;
  u64 b1 = __ballot((o & 0x0000ff00u) != 0);
  u64 b2 = __ballot((o & 0xffff0000u) != 0);
  if ((threadIdx.x & 63) == 0) {
    if (b1) atomicOr(&flag[0], 1);
    if (b2) atomicOr(&flag[1], 1);
  }
}

// Bitpack mask: out[i>>6] bit (i&63) = mask element i != 0
__global__ __launch_bounds__(256) void mask_bits(const u8* __restrict__ raw,
                                                 u64* __restrict__ out,
                                                 const int* __restrict__ flag) {
  int f = flag[0] ? 2 : (flag[1] ? 1 : 0);
  int i = blockIdx.x * 256 + threadIdx.x;
  bool bit;
  if (f == 2)      bit = raw[i] != 0;
  else if (f == 0) bit = ((const int*)raw)[i] != 0;
  else             bit = ((const float*)raw)[i] != 0.0f;
  u64 b = __ballot(bit);
  if ((threadIdx.x & 63) == 0) out[i >> 6] = b;
}

// ---------------------------------------------------------------------------
// Convert 4 weight matrices fp32 -> bf16 (1M elems each)
// ---------------------------------------------------------------------------
__global__ __launch_bounds__(256) void conv_w(const float* __restrict__ W0, const float* __restrict__ W1,
                                              const float* __restrict__ W2, const float* __restrict__ W3,
                                              u16* __restrict__ o0, u16* __restrict__ o1,
                                              u16* __restrict__ o2, u16* __restrict__ o3) {
  int zz = blockIdx.z;
  const float* W = zz == 0 ? W0 : zz == 1 ? W1 : zz == 2 ? W2 : W3;
  u16* o = zz == 0 ? o0 : zz == 1 ? o1 : zz == 2 ? o2 : o3;
  int i = (blockIdx.x * 256 + threadIdx.x) * 8;
  float4 a = *(const float4*)(W + i), b2 = *(const float4*)(W + i + 4);
  uint4 t;
  t.x = pk2(f2b(a.x), f2b(a.y));   t.y = pk2(f2b(a.z), f2b(a.w));
  t.z = pk2(f2b(b2.x), f2b(b2.y)); t.w = pk2(f2b(b2.z), f2b(b2.w));
  *(uint4*)(o + i) = t;
}

// ---------------------------------------------------------------------------
// NT GEMM body: C[m][n] = cscale * sum_k A[m][k]*B[n][k]
// 128x128 tile, BK=64, 4 waves, double-buffered LDS, T2 swizzle.
// AF32/BF32: that operand is fp32 in global, reg-staged (T14: issue float4
// loads at loop top, cvtpk+swizzled ds_write into the other buffer after
// MFMA). bf16 operands use glds16. LDS image identical for both paths:
// LDS[row][col8] = global[row][col8 ^ (row&7)].
// ---------------------------------------------------------------------------
template<int AF32, int BF32, int CF32>
__device__ __forceinline__ void gemm_body(
    const void* __restrict__ Av, const void* __restrict__ Bv, void* __restrict__ Cv,
    int N, int K, int m0, int n0, float cscale, u16* As, u16* Bs) {
  const int tid = threadIdx.x;
  const int lane = tid & 63, w = tid >> 6;
  const int lr = lane & 15, lg = lane >> 4;
  const int wm = (w >> 1) * 64, wn = (w & 1) * 64;
  const int srow = lane >> 3;
  const int selem = (((lane & 7) ^ srow) << 3);
  const int rsw = (lr & 7) << 3;

  f32x4 acc[4][4];
#pragma unroll
  for (int mi = 0; mi < 4; ++mi)
#pragma unroll
    for (int ni = 0; ni < 4; ++ni)
      acc[mi][ni] = (f32x4){0.f, 0.f, 0.f, 0.f};

  float4 fa0[4], fa1[4], fb0[4], fb1[4];

#define GLDS_SIDE(P, base, k0_, LB)                                            \
  do {                                                                         \
    _Pragma("unroll")                                                          \
    for (int r_ = 0; r_ < 4; ++r_) {                                           \
      const int c_ = w * 4 + r_;                                               \
      const int row_ = c_ * 8 + srow;                                          \
      glds16((const u16*)(P) + (size_t)((base) + row_) * K + (k0_) + selem, (LB) + c_ * 512); \
    }                                                                          \
  } while (0)

#define F32_ISSUE(P, base, k0_, f0, f1)                                        \
  do {                                                                         \
    _Pragma("unroll")                                                          \
    for (int rr = 0; rr < 4; ++rr) {                                           \
      const int ch_ = rr * 256 + tid;                                          \
      const int row_ = ch_ >> 3, col_ = (ch_ & 7) * 8;                         \
      const float* p_ = (const float*)(P) + (size_t)((base) + row_) * K + (k0_) + col_; \
      f0[rr] = *(const float4*)p_;                                             \
      f1[rr] = *(const float4*)(p_ + 4);                                       \
    }                                                                          \
  } while (0)

#define F32_WRITE(LB, f0, f1)                                                  \
  do {                                                                         \
    _Pragma("unroll")                                                          \
    for (int rr = 0; rr < 4; ++rr) {                                           \
      const int ch_ = rr * 256 + tid;                                          \
      const int row_ = ch_ >> 3, col_ = (ch_ & 7) * 8;                         \
      uint4 t_;                                                                \
      t_.x = cvtpk(f0[rr].x, f0[rr].y); t_.y = cvtpk(f0[rr].z, f0[rr].w);      \
      t_.z = cvtpk(f1[rr].x, f1[rr].y); t_.w = cvtpk(f1[rr].z, f1[rr].w);      \
      *(uint4*)&(LB)[row_ * 64 + (col_ ^ ((row_ & 7) << 3))] = t_;             \
    }                                                                          \
  } while (0)

  // prologue: stage tile 0
  if (AF32) { F32_ISSUE(Av, m0, 0, fa0, fa1); F32_WRITE(As, fa0, fa1); }
  else      GLDS_SIDE(Av, m0, 0, As);
  if (BF32) { F32_ISSUE(Bv, n0, 0, fb0, fb1); F32_WRITE(Bs, fb0, fb1); }
  else      GLDS_SIDE(Bv, n0, 0, Bs);
  __syncthreads();

  int cur = 0;
  for (int k0 = 0; k0 < K; k0 += 64) {
    const bool nx = (k0 + 64 < K);
    if (nx) {
      if (AF32) F32_ISSUE(Av, m0, k0 + 64, fa0, fa1);
      else      GLDS_SIDE(Av, m0, k0 + 64, As + (cur ^ 1) * 8192);
      if (BF32) F32_ISSUE(Bv, n0, k0 + 64, fb0, fb1);
      else      GLDS_SIDE(Bv, n0, k0 + 64, Bs + (cur ^ 1) * 8192);
    }
    bf16x8 af[4][2], bfv[4][2];
#pragma unroll
    for (int mi = 0; mi < 4; ++mi)
#pragma unroll
      for (int kk = 0; kk < 2; ++kk)
        af[mi][kk] = *(bf16x8*)&As[cur * 8192 + (wm + mi * 16 + lr) * 64 + ((kk * 32 + lg * 8) ^ rsw)];
#pragma unroll
    for (int ni = 0; ni < 4; ++ni)
#pragma unroll
      for (int kk = 0; kk < 2; ++kk)
        bfv[ni][kk] = *(bf16x8*)&Bs[cur * 8192 + (wn + ni * 16 + lr) * 64 + ((kk * 32 + lg * 8) ^ rsw)];
    __builtin_amdgcn_s_setprio(1);
#pragma unroll
    for (int mi = 0; mi < 4; ++mi)
#pragma unroll
      for (int ni = 0; ni < 4; ++ni)
#pragma unroll
        for (int kk = 0; kk < 2; ++kk)
          acc[mi][ni] = __builtin_amdgcn_mfma_f32_16x16x32_bf16(
              af[mi][kk], bfv[ni][kk], acc[mi][ni], 0, 0, 0);
    __builtin_amdgcn_s_setprio(0);
    if (nx) {   // fp32 loads were issued before MFMA; waits inserted on use
      if (AF32) F32_WRITE(As + (cur ^ 1) * 8192, fa0, fa1);
      if (BF32) F32_WRITE(Bs + (cur ^ 1) * 8192, fb0, fb1);
    }
    __syncthreads();
    cur ^= 1;
  }
#undef GLDS_SIDE
#undef F32_ISSUE
#undef F32_WRITE
#pragma unroll
  for (int mi = 0; mi < 4; ++mi)
#pragma unroll
    for (int ni = 0; ni < 4; ++ni)
#pragma unroll
      for (int r = 0; r < 4; ++r) {
        int m = m0 + wm + mi * 16 + lg * 4 + r;
        int n = n0 + wn + ni * 16 + lr;
        float vv = acc[mi][ni][r] * cscale;
        if (CF32) ((float*)Cv)[(size_t)m * N + n] = vv;
        else      ((u16*)Cv)[(size_t)m * N + n] = f2b(vv);
      }
}

// Fused Q,K,V projections from fp32 activations (no conversion pre-pass):
// z=0 Q (scaled), z=1 K, z=2 V-transposed.
__global__ __launch_bounds__(256) void gemm_qkv(
    const float* __restrict__ q, const float* __restrict__ k, const float* __restrict__ v,
    const u16* __restrict__ Wqb, const u16* __restrict__ Wkb, const u16* __restrict__ Wvb,
    u16* __restrict__ Qb, u16* __restrict__ Kb, u16* __restrict__ VTb, float qscale) {
  __shared__ __align__(16) u16 As[2 * 8192];
  __shared__ __align__(16) u16 Bs[2 * 8192];
  const int z = blockIdx.z;
  if (z < 2) {
    // acts [4096x1024] fp32 = A (reg-staged); weights bf16 = B (glds16)
    const float* act = z ? k : q;
    const u16* Wb = z ? Wkb : Wqb;
    u16* Cb = z ? Kb : Qb;
    const int bxx = blockIdx.x & 7, by = blockIdx.x >> 3;
    gemm_body<1, 0, 0>(act, Wb, Cb, 1024, 1024, by * 128, bxx * 128,
                       z ? 1.0f : qscale, As, Bs);
  } else {
    // VT = Wv . v^T : A = Wv bf16 (glds16), B = v fp32 (reg-staged)
    const int bxx = blockIdx.x & 31, by = blockIdx.x >> 5;
    gemm_body<0, 1, 0>(Wvb, v, VTb, 4096, 1024, by * 128, bxx * 128, 1.0f, As, Bs);
  }
}

// Output projection -> fp32, XCD-swizzled (bijective: 256 = 8 x 32)
__global__ __launch_bounds__(256) void gemm_o(
    const u16* __restrict__ Ob, const u16* __restrict__ Wob, float* __restrict__ C) {
  __shared__ __align__(16) u16 As[2 * 8192];
  __shared__ __align__(16) u16 Bs[2 * 8192];
  const int idx = blockIdx.x;
  const int xcd = idx & 7, r = idx >> 3;
  const int mblk = xcd * 4 + (r & 3), nblk = r >> 2;
  gemm_body<0, 0, 1>(Ob, Wob, C, 1024, 1024, mblk * 128, nblk * 128, 1.0f, As, Bs);
}

// ---------------------------------------------------------------------------
// Flash attention v12 (proven): K-split x3, tile ranges {0..10,10..21,21..32},
// additive partials (no max-tracking), 32x32 swapped QK^T + permlane32_swap,
// row-sums via ones-MFMA, double-buffered LDS. grid = 1536, 256 thr.
// ---------------------------------------------------------------------------
__global__ __launch_bounds__(256, 4) void flash12(const u16* __restrict__ Q,
                                                  const u16* __restrict__ K,
                                                  const u16* __restrict__ VT,
                                                  const u64* __restrict__ mpk,
                                                  u16* __restrict__ O0,
                                                  u16* __restrict__ O1,
                                                  u16* __restrict__ O2,
                                                  float* __restrict__ Lp) {
  __shared__ __align__(16) u16 Ks[2][4096];   // [64 key][64 d], swizzled
  __shared__ __align__(16) u16 Vs[2][4096];   // [64 d][64 key], swizzled
  const int tid = threadIdx.x, lane = tid & 63, w = tid >> 6;
  const int c = lane & 31, h = lane >> 5;
  const int bid = blockIdx.x;
  const int xcd = bid & 7, idx = bid >> 3;        // idx 0..191
  const int gl = idx >> 4, qblk = idx & 15;       // gl 0..11
  const int group = xcd * 12 + gl;                // 0..95
  const int split = group % 3;
  const int hb = group / 3;                       // 0..31
  const int head = hb & 15, b = hb >> 4;
  const int qw = qblk * 128 + w * 32;
  const int kt0 = (split * 32) / 3;               // 0, 10, 21
  const int ktn = ((split + 1) * 32) / 3;         // 10, 21, 32
  const int nt = ktn - kt0;
  const size_t kbase = (size_t)b * 2048 * 1024 + (size_t)head * 64;
  const size_t vbase = (size_t)head * 64 * 4096 + (size_t)b * 2048;
  const int srow = lane >> 3;
  const int selem = (((lane & 7) ^ srow) << 3);
  const int rswc = (c & 7) << 3;

  bf16x8 qf[4];
#pragma unroll
  for (int kd = 0; kd < 4; ++kd)
    qf[kd] = *(const bf16x8*)&Q[kbase + (size_t)(qw + c) * 1024 + 16 * kd + 8 * h];

  union { u32 u[4]; bf16x8 v; } ones;
#pragma unroll
  for (int i = 0; i < 4; ++i) ones.u[i] = 0x3f803f80u;

  f32x16 accO0, accO1, accL;
#pragma unroll
  for (int i = 0; i < 16; ++i) { accO0[i] = 0.f; accO1[i] = 0.f; accL[i] = 0.f; }

  const u64* mrp = mpk + ((size_t)b * 2048 + qw + c) * 32;

#define STAGE(buf, t)                                                          \
  do {                                                                         \
    const int k0_ = (t) * 64;                                                  \
    _Pragma("unroll")                                                          \
    for (int r_ = 0; r_ < 2; ++r_) {                                           \
      const int c_ = w * 2 + r_;                                               \
      const int row_ = c_ * 8 + srow;                                          \
      glds16(K + kbase + (size_t)(k0_ + row_) * 1024 + selem, &Ks[buf][c_ * 512]); \
    }                                                                          \
    _Pragma("unroll")                                                          \
    for (int r_ = 0; r_ < 2; ++r_) {                                           \
      const int c_ = w * 2 + r_;                                               \
      const int row_ = c_ * 8 + srow;                                          \
      glds16(VT + vbase + (size_t)row_ * 4096 + k0_ + selem, &Vs[buf][c_ * 512]); \
    }                                                                          \
  } while (0)

  STAGE(0, kt0);
  u64 mb_next = mrp[kt0];
  __syncthreads();

  int cur = 0;
  for (int t = 0; t < nt; ++t) {
    const u64 mb = mb_next;
    if (t + 1 < nt) {
      STAGE(cur ^ 1, kt0 + t + 1);
      mb_next = mrp[kt0 + t + 1];
    }
    const u16* ks = Ks[cur];
    const u16* vs = Vs[cur];
    f32x16 s0, s1;
#pragma unroll
    for (int i = 0; i < 16; ++i) { s0[i] = 0.f; s1[i] = 0.f; }
    __builtin_amdgcn_s_setprio(1);
#pragma unroll
    for (int kd = 0; kd < 4; ++kd) {
      bf16x8 kf0 = *(bf16x8*)&ks[c * 64 + ((16 * kd + 8 * h) ^ rswc)];
      s0 = __builtin_amdgcn_mfma_f32_32x32x16_bf16(kf0, qf[kd], s0, 0, 0, 0);
      bf16x8 kf1 = *(bf16x8*)&ks[(32 + c) * 64 + ((16 * kd + 8 * h) ^ rswc)];
      s1 = __builtin_amdgcn_mfma_f32_32x32x16_bf16(kf1, qf[kd], s1, 0, 0, 0);
    }
    __builtin_amdgcn_s_setprio(0);
    u32 pw[2][4][2];
#pragma unroll
    for (int kb = 0; kb < 2; ++kb) {
      const u32 m32 = (u32)(mb >> (32 * kb + 4 * h));
      float pp[16];
#pragma unroll
      for (int g = 0; g < 4; ++g)
#pragma unroll
        for (int r = 0; r < 4; ++r) {
          float e = fexp2(kb == 0 ? s0[4 * g + r] : s1[4 * g + r]);
          pp[4 * g + r] = ((m32 >> (8 * g + r)) & 1) ? 0.0f : e;
        }
#pragma unroll
      for (int g = 0; g < 4; ++g)
#pragma unroll
        for (int hh = 0; hh < 2; ++hh)
          pw[kb][g][hh] = cvtpk(pp[4 * g + 2 * hh], pp[4 * g + 2 * hh + 1]);
    }
    __builtin_amdgcn_s_setprio(1);
#pragma unroll
    for (int kb = 0; kb < 2; ++kb)
#pragma unroll
      for (int s = 0; s < 2; ++s) {
        u32 w0 = pw[kb][2 * s][0], w2 = pw[kb][2 * s + 1][0];
        swap32(w0, w2);
        u32 w1 = pw[kb][2 * s][1], w3 = pw[kb][2 * s + 1][1];
        swap32(w1, w3);
        union { u32 u[4]; bf16x8 v; } af;
        af.u[0] = w0; af.u[1] = w1; af.u[2] = w2; af.u[3] = w3;
        const int ksg = kb * 2 + s;
        bf16x8 vf0 = *(bf16x8*)&vs[c * 64 + ((16 * ksg + 8 * h) ^ rswc)];
        accO0 = __builtin_amdgcn_mfma_f32_32x32x16_bf16(af.v, vf0, accO0, 0, 0, 0);
        bf16x8 vf1 = *(bf16x8*)&vs[(32 + c) * 64 + ((16 * ksg + 8 * h) ^ rswc)];
        accO1 = __builtin_amdgcn_mfma_f32_32x32x16_bf16(af.v, vf1, accO1, 0, 0, 0);
        accL  = __builtin_amdgcn_mfma_f32_32x32x16_bf16(af.v, ones.v, accL, 0, 0, 0);
      }
    __builtin_amdgcn_s_setprio(0);
    __syncthreads();
    cur ^= 1;
  }
#undef STAGE
  u16* Op = split == 0 ? O0 : split == 1 ? O1 : O2;
  const size_t obase = (size_t)b * 2048 + qw;
#pragma unroll
  for (int g = 0; g < 4; ++g)
#pragma unroll
    for (int r = 0; r < 4; ++r) {
      const int qrow = r + 8 * g + 4 * h;
      const size_t row = obase + qrow;
      const size_t base = row * 1024 + (size_t)head * 64 + c;
      Op[base]      = f2b(accO0[4 * g + r]);
      Op[base + 32] = f2b(accO1[4 * g + r]);
      if (c == 0) Lp[(size_t)split * 65536 + row * 16 + head] = accL[4 * g + r];
    }
}

// ---------------------------------------------------------------------------
// Combine 3 K-split partials: O = (O0+O1+O2) / (L0+L1+L2), bf16 out
// ---------------------------------------------------------------------------
__global__ __launch_bounds__(256) void combine(const u16* __restrict__ O0,
                                               const u16* __restrict__ O1,
                                               const u16* __restrict__ O2,
                                               const float* __restrict__ Lp,
                                               u16* __restrict__ Ob) {
  int gid = blockIdx.x * 256 + threadIdx.x;
  int row = gid >> 7, chb = (gid & 127) * 8;
  int head = chb >> 6;
  float l = Lp[(size_t)row * 16 + head] + Lp[65536 + (size_t)row * 16 + head] +
            Lp[131072 + (size_t)row * 16 + head];
  float inv = 1.0f / l;
  size_t off = (size_t)row * 1024 + chb;
  union { uint4 q; u16 s[8]; } a, b, c2, o;
  a.q  = *(const uint4*)(O0 + off);
  b.q  = *(const uint4*)(O1 + off);
  c2.q = *(const uint4*)(O2 + off);
#pragma unroll
  for (int j = 0; j < 8; ++j)
    o.s[j] = f2b((b2f(a.s[j]) + b2f(b.s[j]) + b2f(c2.s[j])) * inv);
  *(uint4*)(Ob + off) = o.q;
}

// ---------------------------------------------------------------------------
extern "C" void kernel_launch(void* const* d_in, const int* in_sizes, int n_in,
                              void* d_out, int out_size, void* d_ws, size_t ws_size,
                              hipStream_t stream) {
  const float* q    = (const float*)d_in[0];
  const float* k    = (const float*)d_in[1];
  const float* v    = (const float*)d_in[2];
  const u8*    mask = (const u8*)d_in[3];
  const float* Wq   = (const float*)d_in[4];
  const float* Wk   = (const float*)d_in[5];
  const float* Wv   = (const float*)d_in[6];
  const float* Wo   = (const float*)d_in[7];

  u8* ws = (u8*)d_ws;
  int* flag = (int*)ws;                         // 256 B
  u64* mpk  = (u64*)(ws + 256);                 // 1 MB
  u16* Wqb  = (u16*)(ws + 256 + (1u << 20));    // 2 MB each
  u16* Wkb  = Wqb + (1 << 20);
  u16* Wvb  = Wkb + (1 << 20);
  u16* Wob  = Wvb + (1 << 20);
  const size_t NE = (size_t)4096 * 1024;
  u16* O2   = Wob + (1 << 20);                  // 8 MB: split-2 partial
  u16* Qb   = O2 + NE;                          // 8 MB each
  u16* Kb   = Qb + NE;
  u16* VTb  = Kb + NE;                          // ws total ~41.3 MB
  u16* O0   = (u16*)d_out;                      // d_out as scratch: partials 0,1
  u16* O1   = O0 + NE;
  float* Lp = (float*)Wqb;                      // 768 KB; Wqb dead after gemm_qkv
  u16* Ob   = Qb;                               // combined out reuses Qb

  const float LOG2E = 1.4426950408889634f;

  hipMemsetAsync(flag, 0, 8, stream);
  mask_detect<<<32, 256, 0, stream>>>(mask, flag);
  mask_bits<<<32768, 256, 0, stream>>>(mask, mpk, flag);
  conv_w<<<dim3(512, 1, 4), 256, 0, stream>>>(Wq, Wk, Wv, Wo, Wqb, Wkb, Wvb, Wob);

  gemm_qkv<<<dim3(256, 1, 3), 256, 0, stream>>>(
      q, k, v, Wqb, Wkb, Wvb, Qb, Kb, VTb, 0.125f * LOG2E);

  flash12<<<1536, 256, 0, stream>>>(Qb, Kb, VTb, mpk, O0, O1, O2, Lp);
  combine<<<2048, 256, 0, stream>>>(O0, O1, O2, Lp, Ob);

  gemm_o<<<dim3(256), 256, 0, stream>>>(Ob, Wob, (float*)d_out);
}

// Round 14
// 159.144 us; speedup vs baseline: 1.0702x; 1.0702x over previous
//
#include <hip/hip_runtime.h>

typedef unsigned short u16;
typedef unsigned int   u32;
typedef unsigned char  u8;
typedef unsigned long long u64;
typedef __attribute__((ext_vector_type(8))) short bf16x8;
typedef __attribute__((ext_vector_type(4))) float f32x4;
typedef __attribute__((ext_vector_type(16))) float f32x16;

// fp32 -> bf16 (round-nearest-even), bit trick
__device__ __forceinline__ u16 f2b(float f) {
  union { float f; u32 u; } v; v.f = f;
  u32 u = v.u;
  return (u16)((u + 0x7fffu + ((u >> 16) & 1u)) >> 16);
}
__device__ __forceinline__ float b2f(u16 x) {
  union { u32 u; float f; } v; v.u = ((u32)x) << 16; return v.f;
}
__device__ __forceinline__ u32 pk2(u16 lo, u16 hi) { return (u32)lo | ((u32)hi << 16); }

// 2^x via v_exp_f32
__device__ __forceinline__ float fexp2(float x) { return __builtin_amdgcn_exp2f(x); }

// pack 2 f32 -> 2 bf16 in one instruction (RNE)
__device__ __forceinline__ u32 cvtpk(float lo, float hi) {
  u32 r;
  asm("v_cvt_pk_bf16_f32 %0, %1, %2" : "=v"(r) : "v"(lo), "v"(hi));
  return r;
}

// v_permlane32_swap_b32: a.hi32lanes <-> b.lo32lanes
__device__ __forceinline__ void swap32(u32& a, u32& b) {
  asm("v_permlane32_swap_b32 %0, %1" : "+v"(a), "+v"(b));
}

// async global->LDS, 16B per lane; LDS dest = wave-uniform base + lane*16
__device__ __forceinline__ void glds16(const u16* g, u16* l) {
  __builtin_amdgcn_global_load_lds((const __attribute__((address_space(1))) void*)g,
                                   (__attribute__((address_space(3))) void*)l, 16, 0, 0);
}

// ---------------------------------------------------------------------------
// Mask dtype detection (parallel): flag[0]!=0 -> bool; else flag[1]!=0 -> f32
// ---------------------------------------------------------------------------
__global__ __launch_bounds__(256) void mask_detect(const u8* __restrict__ raw,
                                                   int* __restrict__ flag) {
  int i = blockIdx.x * 256 + threadIdx.x;
  uint4 x = ((const uint4*)raw)[i];
  u32 o = x.x | x.y | x.z | x.w;
  u64 b1 = __ballot((o & 0x0000ff00u) != 0);
  u64 b2 = __ballot((o & 0xffff0000u) != 0);
  if ((threadIdx.x & 63) == 0) {
    if (b1) atomicOr(&flag[0], 1);
    if (b2) atomicOr(&flag[1], 1);
  }
}

// Bitpack mask: out[i>>6] bit (i&63) = mask element i != 0
__global__ __launch_bounds__(256) void mask_bits(const u8* __restrict__ raw,
                                                 u64* __restrict__ out,
                                                 const int* __restrict__ flag) {
  int f = flag[0] ? 2 : (flag[1] ? 1 : 0);
  int i = blockIdx.x * 256 + threadIdx.x;
  bool bit;
  if (f == 2)      bit = raw[i] != 0;
  else if (f == 0) bit = ((const int*)raw)[i] != 0;
  else             bit = ((const float*)raw)[i] != 0.0f;
  u64 b = __ballot(bit);
  if ((threadIdx.x & 63) == 0) out[i >> 6] = b;
}

// ---------------------------------------------------------------------------
// Convert 4 weight matrices fp32 -> bf16 (1M elems each)
// ---------------------------------------------------------------------------
__global__ __launch_bounds__(256) void conv_w(const float* __restrict__ W0, const float* __restrict__ W1,
                                              const float* __restrict__ W2, const float* __restrict__ W3,
                                              u16* __restrict__ o0, u16* __restrict__ o1,
                                              u16* __restrict__ o2, u16* __restrict__ o3) {
  int zz = blockIdx.z;
  const float* W = zz == 0 ? W0 : zz == 1 ? W1 : zz == 2 ? W2 : W3;
  u16* o = zz == 0 ? o0 : zz == 1 ? o1 : zz == 2 ? o2 : o3;
  int i = (blockIdx.x * 256 + threadIdx.x) * 8;
  float4 a = *(const float4*)(W + i), b2 = *(const float4*)(W + i + 4);
  uint4 t;
  t.x = pk2(f2b(a.x), f2b(a.y));   t.y = pk2(f2b(a.z), f2b(a.w));
  t.z = pk2(f2b(b2.x), f2b(b2.y)); t.w = pk2(f2b(b2.z), f2b(b2.w));
  *(uint4*)(o + i) = t;
}

// ---------------------------------------------------------------------------
// NT GEMM body: C[m][n] = cscale * sum_k A[m][k]*B[n][k]
// 128x128 tile, BK=64, 4 waves, double-buffered LDS, T2 swizzle.
// AF32/BF32: that operand is fp32 in global, reg-staged (T14: issue float4
// loads at loop top, cvtpk+swizzled ds_write into the other buffer after
// MFMA). bf16 operands use glds16. LDS image identical for both paths.
// ---------------------------------------------------------------------------
template<int AF32, int BF32, int CF32>
__device__ __forceinline__ void gemm_body(
    const void* __restrict__ Av, const void* __restrict__ Bv, void* __restrict__ Cv,
    int N, int K, int m0, int n0, float cscale, u16* As, u16* Bs) {
  const int tid = threadIdx.x;
  const int lane = tid & 63, w = tid >> 6;
  const int lr = lane & 15, lg = lane >> 4;
  const int wm = (w >> 1) * 64, wn = (w & 1) * 64;
  const int srow = lane >> 3;
  const int selem = (((lane & 7) ^ srow) << 3);
  const int rsw = (lr & 7) << 3;

  f32x4 acc[4][4];
#pragma unroll
  for (int mi = 0; mi < 4; ++mi)
#pragma unroll
    for (int ni = 0; ni < 4; ++ni)
      acc[mi][ni] = (f32x4){0.f, 0.f, 0.f, 0.f};

  float4 fa0[4], fa1[4], fb0[4], fb1[4];

#define GLDS_SIDE(P, base, k0_, LB)                                            \
  do {                                                                         \
    _Pragma("unroll")                                                          \
    for (int r_ = 0; r_ < 4; ++r_) {                                           \
      const int c_ = w * 4 + r_;                                               \
      const int row_ = c_ * 8 + srow;                                          \
      glds16((const u16*)(P) + (size_t)((base) + row_) * K + (k0_) + selem, (LB) + c_ * 512); \
    }                                                                          \
  } while (0)

#define F32_ISSUE(P, base, k0_, f0, f1)                                        \
  do {                                                                         \
    _Pragma("unroll")                                                          \
    for (int rr = 0; rr < 4; ++rr) {                                           \
      const int ch_ = rr * 256 + tid;                                          \
      const int row_ = ch_ >> 3, col_ = (ch_ & 7) * 8;                         \
      const float* p_ = (const float*)(P) + (size_t)((base) + row_) * K + (k0_) + col_; \
      f0[rr] = *(const float4*)p_;                                             \
      f1[rr] = *(const float4*)(p_ + 4);                                       \
    }                                                                          \
  } while (0)

#define F32_WRITE(LB, f0, f1)                                                  \
  do {                                                                         \
    _Pragma("unroll")                                                          \
    for (int rr = 0; rr < 4; ++rr) {                                           \
      const int ch_ = rr * 256 + tid;                                          \
      const int row_ = ch_ >> 3, col_ = (ch_ & 7) * 8;                         \
      uint4 t_;                                                                \
      t_.x = cvtpk(f0[rr].x, f0[rr].y); t_.y = cvtpk(f0[rr].z, f0[rr].w);      \
      t_.z = cvtpk(f1[rr].x, f1[rr].y); t_.w = cvtpk(f1[rr].z, f1[rr].w);      \
      *(uint4*)&(LB)[row_ * 64 + (col_ ^ ((row_ & 7) << 3))] = t_;             \
    }                                                                          \
  } while (0)

  // prologue: stage tile 0
  if (AF32) { F32_ISSUE(Av, m0, 0, fa0, fa1); F32_WRITE(As, fa0, fa1); }
  else      GLDS_SIDE(Av, m0, 0, As);
  if (BF32) { F32_ISSUE(Bv, n0, 0, fb0, fb1); F32_WRITE(Bs, fb0, fb1); }
  else      GLDS_SIDE(Bv, n0, 0, Bs);
  __syncthreads();

  int cur = 0;
  for (int k0 = 0; k0 < K; k0 += 64) {
    const bool nx = (k0 + 64 < K);
    if (nx) {
      if (AF32) F32_ISSUE(Av, m0, k0 + 64, fa0, fa1);
      else      GLDS_SIDE(Av, m0, k0 + 64, As + (cur ^ 1) * 8192);
      if (BF32) F32_ISSUE(Bv, n0, k0 + 64, fb0, fb1);
      else      GLDS_SIDE(Bv, n0, k0 + 64, Bs + (cur ^ 1) * 8192);
    }
    bf16x8 af[4][2], bfv[4][2];
#pragma unroll
    for (int mi = 0; mi < 4; ++mi)
#pragma unroll
      for (int kk = 0; kk < 2; ++kk)
        af[mi][kk] = *(bf16x8*)&As[cur * 8192 + (wm + mi * 16 + lr) * 64 + ((kk * 32 + lg * 8) ^ rsw)];
#pragma unroll
    for (int ni = 0; ni < 4; ++ni)
#pragma unroll
      for (int kk = 0; kk < 2; ++kk)
        bfv[ni][kk] = *(bf16x8*)&Bs[cur * 8192 + (wn + ni * 16 + lr) * 64 + ((kk * 32 + lg * 8) ^ rsw)];
    __builtin_amdgcn_s_setprio(1);
#pragma unroll
    for (int mi = 0; mi < 4; ++mi)
#pragma unroll
      for (int ni = 0; ni < 4; ++ni)
#pragma unroll
        for (int kk = 0; kk < 2; ++kk)
          acc[mi][ni] = __builtin_amdgcn_mfma_f32_16x16x32_bf16(
              af[mi][kk], bfv[ni][kk], acc[mi][ni], 0, 0, 0);
    __builtin_amdgcn_s_setprio(0);
    if (nx) {   // fp32 loads were issued before MFMA; waits inserted on use
      if (AF32) F32_WRITE(As + (cur ^ 1) * 8192, fa0, fa1);
      if (BF32) F32_WRITE(Bs + (cur ^ 1) * 8192, fb0, fb1);
    }
    __syncthreads();
    cur ^= 1;
  }
#undef GLDS_SIDE
#undef F32_ISSUE
#undef F32_WRITE
#pragma unroll
  for (int mi = 0; mi < 4; ++mi)
#pragma unroll
    for (int ni = 0; ni < 4; ++ni)
#pragma unroll
      for (int r = 0; r < 4; ++r) {
        int m = m0 + wm + mi * 16 + lg * 4 + r;
        int n = n0 + wn + ni * 16 + lr;
        float vv = acc[mi][ni][r] * cscale;
        if (CF32) ((float*)Cv)[(size_t)m * N + n] = vv;
        else      ((u16*)Cv)[(size_t)m * N + n] = f2b(vv);
      }
}

// Fused Q,K,V projections from fp32 activations. XCD-swizzled: the 8 blocks
// sharing one fp32 panel (same panel idx, 8 output blocks) are co-resident
// on ONE XCD -> the panel is HBM-fetched once and L2-served (round-13 fix:
// without this, each XCD refetched the panel -> 150MB FETCH).
// z=0 Q (scaled), z=1 K, z=2 V-transposed.
__global__ __launch_bounds__(256) void gemm_qkv(
    const float* __restrict__ q, const float* __restrict__ k, const float* __restrict__ v,
    const u16* __restrict__ Wqb, const u16* __restrict__ Wkb, const u16* __restrict__ Wvb,
    u16* __restrict__ Qb, u16* __restrict__ Kb, u16* __restrict__ VTb, float qscale) {
  __shared__ __align__(16) u16 As[2 * 8192];
  __shared__ __align__(16) u16 Bs[2 * 8192];
  const int z = blockIdx.z;
  const int xcd = blockIdx.x & 7, r = blockIdx.x >> 3;   // bijective: 8*4*8=256
  const int pblk = xcd * 4 + (r & 3);                    // fp32 panel 0..31
  const int oblk = r >> 2;                               // 0..7
  if (z < 2) {
    // acts [4096x1024] fp32 = A (reg-staged, m-panel = pblk); weights bf16 = B
    const float* act = z ? k : q;
    const u16* Wb = z ? Wkb : Wqb;
    u16* Cb = z ? Kb : Qb;
    gemm_body<1, 0, 0>(act, Wb, Cb, 1024, 1024, pblk * 128, oblk * 128,
                       z ? 1.0f : qscale, As, Bs);
  } else {
    // VT = Wv . v^T : A = Wv bf16 (glds16), B = v fp32 (reg-staged, n-panel)
    gemm_body<0, 1, 0>(Wvb, v, VTb, 4096, 1024, oblk * 128, pblk * 128, 1.0f, As, Bs);
  }
}

// Output projection -> fp32, XCD-swizzled (bijective: 256 = 8 x 32)
__global__ __launch_bounds__(256) void gemm_o(
    const u16* __restrict__ Ob, const u16* __restrict__ Wob, float* __restrict__ C) {
  __shared__ __align__(16) u16 As[2 * 8192];
  __shared__ __align__(16) u16 Bs[2 * 8192];
  const int idx = blockIdx.x;
  const int xcd = idx & 7, r = idx >> 3;
  const int mblk = xcd * 4 + (r & 3), nblk = r >> 2;
  gemm_body<0, 0, 1>(Ob, Wob, C, 1024, 1024, mblk * 128, nblk * 128, 1.0f, As, Bs);
}

// ---------------------------------------------------------------------------
// Flash attention v12 (proven): K-split x3, tile ranges {0..10,10..21,21..32},
// additive partials (no max-tracking), 32x32 swapped QK^T + permlane32_swap,
// row-sums via ones-MFMA, double-buffered LDS. grid = 1536, 256 thr.
// ---------------------------------------------------------------------------
__global__ __launch_bounds__(256, 4) void flash12(const u16* __restrict__ Q,
                                                  const u16* __restrict__ K,
                                                  const u16* __restrict__ VT,
                                                  const u64* __restrict__ mpk,
                                                  u16* __restrict__ O0,
                                                  u16* __restrict__ O1,
                                                  u16* __restrict__ O2,
                                                  float* __restrict__ Lp) {
  __shared__ __align__(16) u16 Ks[2][4096];   // [64 key][64 d], swizzled
  __shared__ __align__(16) u16 Vs[2][4096];   // [64 d][64 key], swizzled
  const int tid = threadIdx.x, lane = tid & 63, w = tid >> 6;
  const int c = lane & 31, h = lane >> 5;
  const int bid = blockIdx.x;
  const int xcd = bid & 7, idx = bid >> 3;        // idx 0..191
  const int gl = idx >> 4, qblk = idx & 15;       // gl 0..11
  const int group = xcd * 12 + gl;                // 0..95
  const int split = group % 3;
  const int hb = group / 3;                       // 0..31
  const int head = hb & 15, b = hb >> 4;
  const int qw = qblk * 128 + w * 32;
  const int kt0 = (split * 32) / 3;               // 0, 10, 21
  const int ktn = ((split + 1) * 32) / 3;         // 10, 21, 32
  const int nt = ktn - kt0;
  const size_t kbase = (size_t)b * 2048 * 1024 + (size_t)head * 64;
  const size_t vbase = (size_t)head * 64 * 4096 + (size_t)b * 2048;
  const int srow = lane >> 3;
  const int selem = (((lane & 7) ^ srow) << 3);
  const int rswc = (c & 7) << 3;

  bf16x8 qf[4];
#pragma unroll
  for (int kd = 0; kd < 4; ++kd)
    qf[kd] = *(const bf16x8*)&Q[kbase + (size_t)(qw + c) * 1024 + 16 * kd + 8 * h];

  union { u32 u[4]; bf16x8 v; } ones;
#pragma unroll
  for (int i = 0; i < 4; ++i) ones.u[i] = 0x3f803f80u;

  f32x16 accO0, accO1, accL;
#pragma unroll
  for (int i = 0; i < 16; ++i) { accO0[i] = 0.f; accO1[i] = 0.f; accL[i] = 0.f; }

  const u64* mrp = mpk + ((size_t)b * 2048 + qw + c) * 32;

#define STAGE(buf, t)                                                          \
  do {                                                                         \
    const int k0_ = (t) * 64;                                                  \
    _Pragma("unroll")                                                          \
    for (int r_ = 0; r_ < 2; ++r_) {                                           \
      const int c_ = w * 2 + r_;                                               \
      const int row_ = c_ * 8 + srow;                                          \
      glds16(K + kbase + (size_t)(k0_ + row_) * 1024 + selem, &Ks[buf][c_ * 512]); \
    }                                                                          \
    _Pragma("unroll")                                                          \
    for (int r_ = 0; r_ < 2; ++r_) {                                           \
      const int c_ = w * 2 + r_;                                               \
      const int row_ = c_ * 8 + srow;                                          \
      glds16(VT + vbase + (size_t)row_ * 4096 + k0_ + selem, &Vs[buf][c_ * 512]); \
    }                                                                          \
  } while (0)

  STAGE(0, kt0);
  u64 mb_next = mrp[kt0];
  __syncthreads();

  int cur = 0;
  for (int t = 0; t < nt; ++t) {
    const u64 mb = mb_next;
    if (t + 1 < nt) {
      STAGE(cur ^ 1, kt0 + t + 1);
      mb_next = mrp[kt0 + t + 1];
    }
    const u16* ks = Ks[cur];
    const u16* vs = Vs[cur];
    f32x16 s0, s1;
#pragma unroll
    for (int i = 0; i < 16; ++i) { s0[i] = 0.f; s1[i] = 0.f; }
    __builtin_amdgcn_s_setprio(1);
#pragma unroll
    for (int kd = 0; kd < 4; ++kd) {
      bf16x8 kf0 = *(bf16x8*)&ks[c * 64 + ((16 * kd + 8 * h) ^ rswc)];
      s0 = __builtin_amdgcn_mfma_f32_32x32x16_bf16(kf0, qf[kd], s0, 0, 0, 0);
      bf16x8 kf1 = *(bf16x8*)&ks[(32 + c) * 64 + ((16 * kd + 8 * h) ^ rswc)];
      s1 = __builtin_amdgcn_mfma_f32_32x32x16_bf16(kf1, qf[kd], s1, 0, 0, 0);
    }
    __builtin_amdgcn_s_setprio(0);
    u32 pw[2][4][2];
#pragma unroll
    for (int kb = 0; kb < 2; ++kb) {
      const u32 m32 = (u32)(mb >> (32 * kb + 4 * h));
      float pp[16];
#pragma unroll
      for (int g = 0; g < 4; ++g)
#pragma unroll
        for (int r = 0; r < 4; ++r) {
          float e = fexp2(kb == 0 ? s0[4 * g + r] : s1[4 * g + r]);
          pp[4 * g + r] = ((m32 >> (8 * g + r)) & 1) ? 0.0f : e;
        }
#pragma unroll
      for (int g = 0; g < 4; ++g)
#pragma unroll
        for (int hh = 0; hh < 2; ++hh)
          pw[kb][g][hh] = cvtpk(pp[4 * g + 2 * hh], pp[4 * g + 2 * hh + 1]);
    }
    __builtin_amdgcn_s_setprio(1);
#pragma unroll
    for (int kb = 0; kb < 2; ++kb)
#pragma unroll
      for (int s = 0; s < 2; ++s) {
        u32 w0 = pw[kb][2 * s][0], w2 = pw[kb][2 * s + 1][0];
        swap32(w0, w2);
        u32 w1 = pw[kb][2 * s][1], w3 = pw[kb][2 * s + 1][1];
        swap32(w1, w3);
        union { u32 u[4]; bf16x8 v; } af;
        af.u[0] = w0; af.u[1] = w1; af.u[2] = w2; af.u[3] = w3;
        const int ksg = kb * 2 + s;
        bf16x8 vf0 = *(bf16x8*)&vs[c * 64 + ((16 * ksg + 8 * h) ^ rswc)];
        accO0 = __builtin_amdgcn_mfma_f32_32x32x16_bf16(af.v, vf0, accO0, 0, 0, 0);
        bf16x8 vf1 = *(bf16x8*)&vs[(32 + c) * 64 + ((16 * ksg + 8 * h) ^ rswc)];
        accO1 = __builtin_amdgcn_mfma_f32_32x32x16_bf16(af.v, vf1, accO1, 0, 0, 0);
        accL  = __builtin_amdgcn_mfma_f32_32x32x16_bf16(af.v, ones.v, accL, 0, 0, 0);
      }
    __builtin_amdgcn_s_setprio(0);
    __syncthreads();
    cur ^= 1;
  }
#undef STAGE
  u16* Op = split == 0 ? O0 : split == 1 ? O1 : O2;
  const size_t obase = (size_t)b * 2048 + qw;
#pragma unroll
  for (int g = 0; g < 4; ++g)
#pragma unroll
    for (int r = 0; r < 4; ++r) {
      const int qrow = r + 8 * g + 4 * h;
      const size_t row = obase + qrow;
      const size_t base = row * 1024 + (size_t)head * 64 + c;
      Op[base]      = f2b(accO0[4 * g + r]);
      Op[base + 32] = f2b(accO1[4 * g + r]);
      if (c == 0) Lp[(size_t)split * 65536 + row * 16 + head] = accL[4 * g + r];
    }
}

// ---------------------------------------------------------------------------
// Combine 3 K-split partials: O = (O0+O1+O2) / (L0+L1+L2), bf16 out
// ---------------------------------------------------------------------------
__global__ __launch_bounds__(256) void combine(const u16* __restrict__ O0,
                                               const u16* __restrict__ O1,
                                               const u16* __restrict__ O2,
                                               const float* __restrict__ Lp,
                                               u16* __restrict__ Ob) {
  int gid = blockIdx.x * 256 + threadIdx.x;
  int row = gid >> 7, chb = (gid & 127) * 8;
  int head = chb >> 6;
  float l = Lp[(size_t)row * 16 + head] + Lp[65536 + (size_t)row * 16 + head] +
            Lp[131072 + (size_t)row * 16 + head];
  float inv = 1.0f / l;
  size_t off = (size_t)row * 1024 + chb;
  union { uint4 q; u16 s[8]; } a, b, c2, o;
  a.q  = *(const uint4*)(O0 + off);
  b.q  = *(const uint4*)(O1 + off);
  c2.q = *(const uint4*)(O2 + off);
#pragma unroll
  for (int j = 0; j < 8; ++j)
    o.s[j] = f2b((b2f(a.s[j]) + b2f(b.s[j]) + b2f(c2.s[j])) * inv);
  *(uint4*)(Ob + off) = o.q;
}

// ---------------------------------------------------------------------------
extern "C" void kernel_launch(void* const* d_in, const int* in_sizes, int n_in,
                              void* d_out, int out_size, void* d_ws, size_t ws_size,
                              hipStream_t stream) {
  const float* q    = (const float*)d_in[0];
  const float* k    = (const float*)d_in[1];
  const float* v    = (const float*)d_in[2];
  const u8*    mask = (const u8*)d_in[3];
  const float* Wq   = (const float*)d_in[4];
  const float* Wk   = (const float*)d_in[5];
  const float* Wv   = (const float*)d_in[6];
  const float* Wo   = (const float*)d_in[7];

  u8* ws = (u8*)d_ws;
  int* flag = (int*)ws;                         // 256 B
  u64* mpk  = (u64*)(ws + 256);                 // 1 MB
  u16* Wqb  = (u16*)(ws + 256 + (1u << 20));    // 2 MB each
  u16* Wkb  = Wqb + (1 << 20);
  u16* Wvb  = Wkb + (1 << 20);
  u16* Wob  = Wvb + (1 << 20);
  const size_t NE = (size_t)4096 * 1024;
  u16* O2   = Wob + (1 << 20);                  // 8 MB: split-2 partial
  u16* Qb   = O2 + NE;                          // 8 MB each
  u16* Kb   = Qb + NE;
  u16* VTb  = Kb + NE;                          // ws total ~41.3 MB
  u16* O0   = (u16*)d_out;                      // d_out as scratch: partials 0,1
  u16* O1   = O0 + NE;
  float* Lp = (float*)Wqb;                      // 768 KB; Wqb dead after gemm_qkv
  u16* Ob   = Qb;                               // combined out reuses Qb

  const float LOG2E = 1.4426950408889634f;

  hipMemsetAsync(flag, 0, 8, stream);
  mask_detect<<<32, 256, 0, stream>>>(mask, flag);
  mask_bits<<<32768, 256, 0, stream>>>(mask, mpk, flag);
  conv_w<<<dim3(512, 1, 4), 256, 0, stream>>>(Wq, Wk, Wv, Wo, Wqb, Wkb, Wvb, Wob);

  gemm_qkv<<<dim3(256, 1, 3), 256, 0, stream>>>(
      q, k, v, Wqb, Wkb, Wvb, Qb, Kb, VTb, 0.125f * LOG2E);

  flash12<<<1536, 256, 0, stream>>>(Qb, Kb, VTb, mpk, O0, O1, O2, Lp);
  combine<<<2048, 256, 0, stream>>>(O0, O1, O2, Lp, Ob);

  gemm_o<<<dim3(256), 256, 0, stream>>>(Ob, Wob, (float*)d_out);
}

// Round 15
// 157.049 us; speedup vs baseline: 1.0845x; 1.0133x over previous
//
#include <hip/hip_runtime.h>

typedef unsigned short u16;
typedef unsigned int   u32;
typedef unsigned char  u8;
typedef unsigned long long u64;
typedef __attribute__((ext_vector_type(8))) short bf16x8;
typedef __attribute__((ext_vector_type(4))) float f32x4;
typedef __attribute__((ext_vector_type(16))) float f32x16;

// fp32 -> bf16 (round-nearest-even), bit trick
__device__ __forceinline__ u16 f2b(float f) {
  union { float f; u32 u; } v; v.f = f;
  u32 u = v.u;
  return (u16)((u + 0x7fffu + ((u >> 16) & 1u)) >> 16);
}
__device__ __forceinline__ float b2f(u16 x) {
  union { u32 u; float f; } v; v.u = ((u32)x) << 16; return v.f;
}
__device__ __forceinline__ u32 pk2(u16 lo, u16 hi) { return (u32)lo | ((u32)hi << 16); }

// 2^x via v_exp_f32
__device__ __forceinline__ float fexp2(float x) { return __builtin_amdgcn_exp2f(x); }

// pack 2 f32 -> 2 bf16 in one instruction (RNE)
__device__ __forceinline__ u32 cvtpk(float lo, float hi) {
  u32 r;
  asm("v_cvt_pk_bf16_f32 %0, %1, %2" : "=v"(r) : "v"(lo), "v"(hi));
  return r;
}

// v_permlane32_swap_b32: a.hi32lanes <-> b.lo32lanes
__device__ __forceinline__ void swap32(u32& a, u32& b) {
  asm("v_permlane32_swap_b32 %0, %1" : "+v"(a), "+v"(b));
}

// async global->LDS, 16B per lane; LDS dest = wave-uniform base + lane*16
__device__ __forceinline__ void glds16(const u16* g, u16* l) {
  __builtin_amdgcn_global_load_lds((const __attribute__((address_space(1))) void*)g,
                                   (__attribute__((address_space(3))) void*)l, 16, 0, 0);
}

// ---------------------------------------------------------------------------
// Mask dtype detection (parallel): flag[0]!=0 -> bool; else flag[1]!=0 -> f32
// ---------------------------------------------------------------------------
__global__ __launch_bounds__(256) void mask_detect(const u8* __restrict__ raw,
                                                   int* __restrict__ flag) {
  int i = blockIdx.x * 256 + threadIdx.x;
  uint4 x = ((const uint4*)raw)[i];
  u32 o = x.x | x.y | x.z | x.w;
  u64 b1 = __ballot((o & 0x0000ff00u) != 0);
  u64 b2 = __ballot((o & 0xffff0000u) != 0);
  if ((threadIdx.x & 63) == 0) {
    if (b1) atomicOr(&flag[0], 1);
    if (b2) atomicOr(&flag[1], 1);
  }
}

// Bitpack mask: out[i>>6] bit (i&63) = mask element i != 0
__global__ __launch_bounds__(256) void mask_bits(const u8* __restrict__ raw,
                                                 u64* __restrict__ out,
                                                 const int* __restrict__ flag) {
  int f = flag[0] ? 2 : (flag[1] ? 1 : 0);
  int i = blockIdx.x * 256 + threadIdx.x;
  bool bit;
  if (f == 2)      bit = raw[i] != 0;
  else if (f == 0) bit = ((const int*)raw)[i] != 0;
  else             bit = ((const float*)raw)[i] != 0.0f;
  u64 b = __ballot(bit);
  if ((threadIdx.x & 63) == 0) out[i >> 6] = b;
}

// ---------------------------------------------------------------------------
// Convert 4 weight matrices fp32 -> bf16 (1M elems each)
// ---------------------------------------------------------------------------
__global__ __launch_bounds__(256) void conv_w(const float* __restrict__ W0, const float* __restrict__ W1,
                                              const float* __restrict__ W2, const float* __restrict__ W3,
                                              u16* __restrict__ o0, u16* __restrict__ o1,
                                              u16* __restrict__ o2, u16* __restrict__ o3) {
  int zz = blockIdx.z;
  const float* W = zz == 0 ? W0 : zz == 1 ? W1 : zz == 2 ? W2 : W3;
  u16* o = zz == 0 ? o0 : zz == 1 ? o1 : zz == 2 ? o2 : o3;
  int i = (blockIdx.x * 256 + threadIdx.x) * 8;
  float4 a = *(const float4*)(W + i), b2 = *(const float4*)(W + i + 4);
  uint4 t;
  t.x = pk2(f2b(a.x), f2b(a.y));   t.y = pk2(f2b(a.z), f2b(a.w));
  t.z = pk2(f2b(b2.x), f2b(b2.y)); t.w = pk2(f2b(b2.z), f2b(b2.w));
  *(uint4*)(o + i) = t;
}

// ---------------------------------------------------------------------------
// NT GEMM body: C[m][n] = cscale * sum_k A[m][k]*B[n][k]
// 128x128 tile, BK=64, 4 waves, T2 swizzle.
// DBUF=1: double-buffered LDS, 1 barrier/K-step (round-14 proven; for
//   grids at 1 block/CU where occupancy can't rise).
// DBUF=0: single-buffered LDS (32 KB), 2 barriers/K-step (m97 structure) ->
//   3-4 blocks/CU co-resident; barrier drains covered by TLP.
// AF32/BF32: operand is fp32 in global, reg-staged (T14: float4 loads issued
// under MFMA, cvtpk+swizzled ds_write at staging point). bf16: glds16.
// ---------------------------------------------------------------------------
template<int AF32, int BF32, int CF32, int DBUF>
__device__ __forceinline__ void gemm_body(
    const void* __restrict__ Av, const void* __restrict__ Bv, void* __restrict__ Cv,
    int N, int K, int m0, int n0, float cscale, u16* As, u16* Bs) {
  const int tid = threadIdx.x;
  const int lane = tid & 63, w = tid >> 6;
  const int lr = lane & 15, lg = lane >> 4;
  const int wm = (w >> 1) * 64, wn = (w & 1) * 64;
  const int srow = lane >> 3;
  const int selem = (((lane & 7) ^ srow) << 3);
  const int rsw = (lr & 7) << 3;

  f32x4 acc[4][4];
#pragma unroll
  for (int mi = 0; mi < 4; ++mi)
#pragma unroll
    for (int ni = 0; ni < 4; ++ni)
      acc[mi][ni] = (f32x4){0.f, 0.f, 0.f, 0.f};

  float4 fa0[4], fa1[4], fb0[4], fb1[4];

#define GLDS_SIDE(P, base, k0_, LB)                                            \
  do {                                                                         \
    _Pragma("unroll")                                                          \
    for (int r_ = 0; r_ < 4; ++r_) {                                           \
      const int c_ = w * 4 + r_;                                               \
      const int row_ = c_ * 8 + srow;                                          \
      glds16((const u16*)(P) + (size_t)((base) + row_) * K + (k0_) + selem, (LB) + c_ * 512); \
    }                                                                          \
  } while (0)

#define F32_ISSUE(P, base, k0_, f0, f1)                                        \
  do {                                                                         \
    _Pragma("unroll")                                                          \
    for (int rr = 0; rr < 4; ++rr) {                                           \
      const int ch_ = rr * 256 + tid;                                          \
      const int row_ = ch_ >> 3, col_ = (ch_ & 7) * 8;                         \
      const float* p_ = (const float*)(P) + (size_t)((base) + row_) * K + (k0_) + col_; \
      f0[rr] = *(const float4*)p_;                                             \
      f1[rr] = *(const float4*)(p_ + 4);                                       \
    }                                                                          \
  } while (0)

#define F32_WRITE(LB, f0, f1)                                                  \
  do {                                                                         \
    _Pragma("unroll")                                                          \
    for (int rr = 0; rr < 4; ++rr) {                                           \
      const int ch_ = rr * 256 + tid;                                          \
      const int row_ = ch_ >> 3, col_ = (ch_ & 7) * 8;                         \
      uint4 t_;                                                                \
      t_.x = cvtpk(f0[rr].x, f0[rr].y); t_.y = cvtpk(f0[rr].z, f0[rr].w);      \
      t_.z = cvtpk(f1[rr].x, f1[rr].y); t_.w = cvtpk(f1[rr].z, f1[rr].w);      \
      *(uint4*)&(LB)[row_ * 64 + (col_ ^ ((row_ & 7) << 3))] = t_;             \
    }                                                                          \
  } while (0)

#define FRAG_MFMA(bufA, bufB)                                                  \
  do {                                                                         \
    bf16x8 af[4][2], bfv[4][2];                                                \
    _Pragma("unroll")                                                          \
    for (int mi = 0; mi < 4; ++mi)                                             \
      _Pragma("unroll")                                                        \
      for (int kk = 0; kk < 2; ++kk)                                           \
        af[mi][kk] = *(bf16x8*)&(bufA)[(wm + mi * 16 + lr) * 64 + ((kk * 32 + lg * 8) ^ rsw)]; \
    _Pragma("unroll")                                                          \
    for (int ni = 0; ni < 4; ++ni)                                             \
      _Pragma("unroll")                                                        \
      for (int kk = 0; kk < 2; ++kk)                                           \
        bfv[ni][kk] = *(bf16x8*)&(bufB)[(wn + ni * 16 + lr) * 64 + ((kk * 32 + lg * 8) ^ rsw)]; \
    __builtin_amdgcn_s_setprio(1);                                             \
    _Pragma("unroll")                                                          \
    for (int mi = 0; mi < 4; ++mi)                                             \
      _Pragma("unroll")                                                        \
      for (int ni = 0; ni < 4; ++ni)                                           \
        _Pragma("unroll")                                                      \
        for (int kk = 0; kk < 2; ++kk)                                         \
          acc[mi][ni] = __builtin_amdgcn_mfma_f32_16x16x32_bf16(               \
              af[mi][kk], bfv[ni][kk], acc[mi][ni], 0, 0, 0);                  \
    __builtin_amdgcn_s_setprio(0);                                             \
  } while (0)

  if (DBUF) {
    // ---- double-buffered, 1 barrier per K-step (round-14 proven path) ----
    if (AF32) { F32_ISSUE(Av, m0, 0, fa0, fa1); F32_WRITE(As, fa0, fa1); }
    else      GLDS_SIDE(Av, m0, 0, As);
    if (BF32) { F32_ISSUE(Bv, n0, 0, fb0, fb1); F32_WRITE(Bs, fb0, fb1); }
    else      GLDS_SIDE(Bv, n0, 0, Bs);
    __syncthreads();
    int cur = 0;
    for (int k0 = 0; k0 < K; k0 += 64) {
      const bool nx = (k0 + 64 < K);
      if (nx) {
        if (AF32) F32_ISSUE(Av, m0, k0 + 64, fa0, fa1);
        else      GLDS_SIDE(Av, m0, k0 + 64, As + (cur ^ 1) * 8192);
        if (BF32) F32_ISSUE(Bv, n0, k0 + 64, fb0, fb1);
        else      GLDS_SIDE(Bv, n0, k0 + 64, Bs + (cur ^ 1) * 8192);
      }
      FRAG_MFMA(As + cur * 8192, Bs + cur * 8192);
      if (nx) {
        if (AF32) F32_WRITE(As + (cur ^ 1) * 8192, fa0, fa1);
        if (BF32) F32_WRITE(Bs + (cur ^ 1) * 8192, fb0, fb1);
      }
      __syncthreads();
      cur ^= 1;
    }
  } else {
    // ---- single-buffered (32 KB), 2 barriers per K-step (m97 structure) ----
    if (AF32) F32_ISSUE(Av, m0, 0, fa0, fa1);
    if (BF32) F32_ISSUE(Bv, n0, 0, fb0, fb1);
    for (int k0 = 0; k0 < K; k0 += 64) {
      const bool nx = (k0 + 64 < K);
      __syncthreads();   // all waves done reading the previous tile
      if (AF32) F32_WRITE(As, fa0, fa1);
      else      GLDS_SIDE(Av, m0, k0, As);
      if (BF32) F32_WRITE(Bs, fb0, fb1);
      else      GLDS_SIDE(Bv, n0, k0, Bs);
      __syncthreads();   // staging drained (vmcnt0 + lgkmcnt0)
      if (nx) {          // fp32 loads for the NEXT tile fly across the MFMAs
        if (AF32) F32_ISSUE(Av, m0, k0 + 64, fa0, fa1);
        if (BF32) F32_ISSUE(Bv, n0, k0 + 64, fb0, fb1);
      }
      FRAG_MFMA(As, Bs);
    }
  }
#undef GLDS_SIDE
#undef F32_ISSUE
#undef F32_WRITE
#undef FRAG_MFMA
#pragma unroll
  for (int mi = 0; mi < 4; ++mi)
#pragma unroll
    for (int ni = 0; ni < 4; ++ni)
#pragma unroll
      for (int r = 0; r < 4; ++r) {
        int m = m0 + wm + mi * 16 + lg * 4 + r;
        int n = n0 + wn + ni * 16 + lr;
        float vv = acc[mi][ni][r] * cscale;
        if (CF32) ((float*)Cv)[(size_t)m * N + n] = vv;
        else      ((u16*)Cv)[(size_t)m * N + n] = f2b(vv);
      }
}

// Fused Q,K,V projections from fp32 activations. XCD-swizzled (8 output
// blocks sharing one fp32 panel co-resident on one XCD -> panel L2-served).
// Single-buffered LDS (32 KB) -> 3 blocks/CU. z=0 Q (scaled), z=1 K, z=2 V^T.
__global__ __launch_bounds__(256) void gemm_qkv(
    const float* __restrict__ q, const float* __restrict__ k, const float* __restrict__ v,
    const u16* __restrict__ Wqb, const u16* __restrict__ Wkb, const u16* __restrict__ Wvb,
    u16* __restrict__ Qb, u16* __restrict__ Kb, u16* __restrict__ VTb, float qscale) {
  __shared__ __align__(16) u16 As[8192];
  __shared__ __align__(16) u16 Bs[8192];
  const int z = blockIdx.z;
  const int xcd = blockIdx.x & 7, r = blockIdx.x >> 3;   // bijective: 8*4*8=256
  const int pblk = xcd * 4 + (r & 3);                    // fp32 panel 0..31
  const int oblk = r >> 2;                               // 0..7
  if (z < 2) {
    const float* act = z ? k : q;
    const u16* Wb = z ? Wkb : Wqb;
    u16* Cb = z ? Kb : Qb;
    gemm_body<1, 0, 0, 0>(act, Wb, Cb, 1024, 1024, pblk * 128, oblk * 128,
                          z ? 1.0f : qscale, As, Bs);
  } else {
    gemm_body<0, 1, 0, 0>(Wvb, v, VTb, 4096, 1024, oblk * 128, pblk * 128,
                          1.0f, As, Bs);
  }
}

// Output projection -> fp32, XCD-swizzled; double-buffered (1 block/CU grid)
__global__ __launch_bounds__(256) void gemm_o(
    const u16* __restrict__ Ob, const u16* __restrict__ Wob, float* __restrict__ C) {
  __shared__ __align__(16) u16 As[2 * 8192];
  __shared__ __align__(16) u16 Bs[2 * 8192];
  const int idx = blockIdx.x;
  const int xcd = idx & 7, r = idx >> 3;
  const int mblk = xcd * 4 + (r & 3), nblk = r >> 2;
  gemm_body<0, 0, 1, 1>(Ob, Wob, C, 1024, 1024, mblk * 128, nblk * 128, 1.0f, As, Bs);
}

// ---------------------------------------------------------------------------
// Flash attention v12 (proven): K-split x3, tile ranges {0..10,10..21,21..32},
// additive partials (no max-tracking), 32x32 swapped QK^T + permlane32_swap,
// row-sums via ones-MFMA, double-buffered LDS. grid = 1536, 256 thr.
// ---------------------------------------------------------------------------
__global__ __launch_bounds__(256, 4) void flash12(const u16* __restrict__ Q,
                                                  const u16* __restrict__ K,
                                                  const u16* __restrict__ VT,
                                                  const u64* __restrict__ mpk,
                                                  u16* __restrict__ O0,
                                                  u16* __restrict__ O1,
                                                  u16* __restrict__ O2,
                                                  float* __restrict__ Lp) {
  __shared__ __align__(16) u16 Ks[2][4096];   // [64 key][64 d], swizzled
  __shared__ __align__(16) u16 Vs[2][4096];   // [64 d][64 key], swizzled
  const int tid = threadIdx.x, lane = tid & 63, w = tid >> 6;
  const int c = lane & 31, h = lane >> 5;
  const int bid = blockIdx.x;
  const int xcd = bid & 7, idx = bid >> 3;        // idx 0..191
  const int gl = idx >> 4, qblk = idx & 15;       // gl 0..11
  const int group = xcd * 12 + gl;                // 0..95
  const int split = group % 3;
  const int hb = group / 3;                       // 0..31
  const int head = hb & 15, b = hb >> 4;
  const int qw = qblk * 128 + w * 32;
  const int kt0 = (split * 32) / 3;               // 0, 10, 21
  const int ktn = ((split + 1) * 32) / 3;         // 10, 21, 32
  const int nt = ktn - kt0;
  const size_t kbase = (size_t)b * 2048 * 1024 + (size_t)head * 64;
  const size_t vbase = (size_t)head * 64 * 4096 + (size_t)b * 2048;
  const int srow = lane >> 3;
  const int selem = (((lane & 7) ^ srow) << 3);
  const int rswc = (c & 7) << 3;

  bf16x8 qf[4];
#pragma unroll
  for (int kd = 0; kd < 4; ++kd)
    qf[kd] = *(const bf16x8*)&Q[kbase + (size_t)(qw + c) * 1024 + 16 * kd + 8 * h];

  union { u32 u[4]; bf16x8 v; } ones;
#pragma unroll
  for (int i = 0; i < 4; ++i) ones.u[i] = 0x3f803f80u;

  f32x16 accO0, accO1, accL;
#pragma unroll
  for (int i = 0; i < 16; ++i) { accO0[i] = 0.f; accO1[i] = 0.f; accL[i] = 0.f; }

  const u64* mrp = mpk + ((size_t)b * 2048 + qw + c) * 32;

#define STAGE(buf, t)                                                          \
  do {                                                                         \
    const int k0_ = (t) * 64;                                                  \
    _Pragma("unroll")                                                          \
    for (int r_ = 0; r_ < 2; ++r_) {                                           \
      const int c_ = w * 2 + r_;                                               \
      const int row_ = c_ * 8 + srow;                                          \
      glds16(K + kbase + (size_t)(k0_ + row_) * 1024 + selem, &Ks[buf][c_ * 512]); \
    }                                                                          \
    _Pragma("unroll")                                                          \
    for (int r_ = 0; r_ < 2; ++r_) {                                           \
      const int c_ = w * 2 + r_;                                               \
      const int row_ = c_ * 8 + srow;                                          \
      glds16(VT + vbase + (size_t)row_ * 4096 + k0_ + selem, &Vs[buf][c_ * 512]); \
    }                                                                          \
  } while (0)

  STAGE(0, kt0);
  u64 mb_next = mrp[kt0];
  __syncthreads();

  int cur = 0;
  for (int t = 0; t < nt; ++t) {
    const u64 mb = mb_next;
    if (t + 1 < nt) {
      STAGE(cur ^ 1, kt0 + t + 1);
      mb_next = mrp[kt0 + t + 1];
    }
    const u16* ks = Ks[cur];
    const u16* vs = Vs[cur];
    f32x16 s0, s1;
#pragma unroll
    for (int i = 0; i < 16; ++i) { s0[i] = 0.f; s1[i] = 0.f; }
    __builtin_amdgcn_s_setprio(1);
#pragma unroll
    for (int kd = 0; kd < 4; ++kd) {
      bf16x8 kf0 = *(bf16x8*)&ks[c * 64 + ((16 * kd + 8 * h) ^ rswc)];
      s0 = __builtin_amdgcn_mfma_f32_32x32x16_bf16(kf0, qf[kd], s0, 0, 0, 0);
      bf16x8 kf1 = *(bf16x8*)&ks[(32 + c) * 64 + ((16 * kd + 8 * h) ^ rswc)];
      s1 = __builtin_amdgcn_mfma_f32_32x32x16_bf16(kf1, qf[kd], s1, 0, 0, 0);
    }
    __builtin_amdgcn_s_setprio(0);
    u32 pw[2][4][2];
#pragma unroll
    for (int kb = 0; kb < 2; ++kb) {
      const u32 m32 = (u32)(mb >> (32 * kb + 4 * h));
      float pp[16];
#pragma unroll
      for (int g = 0; g < 4; ++g)
#pragma unroll
        for (int r = 0; r < 4; ++r) {
          float e = fexp2(kb == 0 ? s0[4 * g + r] : s1[4 * g + r]);
          pp[4 * g + r] = ((m32 >> (8 * g + r)) & 1) ? 0.0f : e;
        }
#pragma unroll
      for (int g = 0; g < 4; ++g)
#pragma unroll
        for (int hh = 0; hh < 2; ++hh)
          pw[kb][g][hh] = cvtpk(pp[4 * g + 2 * hh], pp[4 * g + 2 * hh + 1]);
    }
    __builtin_amdgcn_s_setprio(1);
#pragma unroll
    for (int kb = 0; kb < 2; ++kb)
#pragma unroll
      for (int s = 0; s < 2; ++s) {
        u32 w0 = pw[kb][2 * s][0], w2 = pw[kb][2 * s + 1][0];
        swap32(w0, w2);
        u32 w1 = pw[kb][2 * s][1], w3 = pw[kb][2 * s + 1][1];
        swap32(w1, w3);
        union { u32 u[4]; bf16x8 v; } af;
        af.u[0] = w0; af.u[1] = w1; af.u[2] = w2; af.u[3] = w3;
        const int ksg = kb * 2 + s;
        bf16x8 vf0 = *(bf16x8*)&vs[c * 64 + ((16 * ksg + 8 * h) ^ rswc)];
        accO0 = __builtin_amdgcn_mfma_f32_32x32x16_bf16(af.v, vf0, accO0, 0, 0, 0);
        bf16x8 vf1 = *(bf16x8*)&vs[(32 + c) * 64 + ((16 * ksg + 8 * h) ^ rswc)];
        accO1 = __builtin_amdgcn_mfma_f32_32x32x16_bf16(af.v, vf1, accO1, 0, 0, 0);
        accL  = __builtin_amdgcn_mfma_f32_32x32x16_bf16(af.v, ones.v, accL, 0, 0, 0);
      }
    __builtin_amdgcn_s_setprio(0);
    __syncthreads();
    cur ^= 1;
  }
#undef STAGE
  u16* Op = split == 0 ? O0 : split == 1 ? O1 : O2;
  const size_t obase = (size_t)b * 2048 + qw;
#pragma unroll
  for (int g = 0; g < 4; ++g)
#pragma unroll
    for (int r = 0; r < 4; ++r) {
      const int qrow = r + 8 * g + 4 * h;
      const size_t row = obase + qrow;
      const size_t base = row * 1024 + (size_t)head * 64 + c;
      Op[base]      = f2b(accO0[4 * g + r]);
      Op[base + 32] = f2b(accO1[4 * g + r]);
      if (c == 0) Lp[(size_t)split * 65536 + row * 16 + head] = accL[4 * g + r];
    }
}

// ---------------------------------------------------------------------------
// Combine 3 K-split partials: O = (O0+O1+O2) / (L0+L1+L2), bf16 out
// ---------------------------------------------------------------------------
__global__ __launch_bounds__(256) void combine(const u16* __restrict__ O0,
                                               const u16* __restrict__ O1,
                                               const u16* __restrict__ O2,
                                               const float* __restrict__ Lp,
                                               u16* __restrict__ Ob) {
  int gid = blockIdx.x * 256 + threadIdx.x;
  int row = gid >> 7, chb = (gid & 127) * 8;
  int head = chb >> 6;
  float l = Lp[(size_t)row * 16 + head] + Lp[65536 + (size_t)row * 16 + head] +
            Lp[131072 + (size_t)row * 16 + head];
  float inv = 1.0f / l;
  size_t off = (size_t)row * 1024 + chb;
  union { uint4 q; u16 s[8]; } a, b, c2, o;
  a.q  = *(const uint4*)(O0 + off);
  b.q  = *(const uint4*)(O1 + off);
  c2.q = *(const uint4*)(O2 + off);
#pragma unroll
  for (int j = 0; j < 8; ++j)
    o.s[j] = f2b((b2f(a.s[j]) + b2f(b.s[j]) + b2f(c2.s[j])) * inv);
  *(uint4*)(Ob + off) = o.q;
}

// ---------------------------------------------------------------------------
extern "C" void kernel_launch(void* const* d_in, const int* in_sizes, int n_in,
                              void* d_out, int out_size, void* d_ws, size_t ws_size,
                              hipStream_t stream) {
  const float* q    = (const float*)d_in[0];
  const float* k    = (const float*)d_in[1];
  const float* v    = (const float*)d_in[2];
  const u8*    mask = (const u8*)d_in[3];
  const float* Wq   = (const float*)d_in[4];
  const float* Wk   = (const float*)d_in[5];
  const float* Wv   = (const float*)d_in[6];
  const float* Wo   = (const float*)d_in[7];

  u8* ws = (u8*)d_ws;
  int* flag = (int*)ws;                         // 256 B
  u64* mpk  = (u64*)(ws + 256);                 // 1 MB
  u16* Wqb  = (u16*)(ws + 256 + (1u << 20));    // 2 MB each
  u16* Wkb  = Wqb + (1 << 20);
  u16* Wvb  = Wkb + (1 << 20);
  u16* Wob  = Wvb + (1 << 20);
  const size_t NE = (size_t)4096 * 1024;
  u16* O2   = Wob + (1 << 20);                  // 8 MB: split-2 partial
  u16* Qb   = O2 + NE;                          // 8 MB each
  u16* Kb   = Qb + NE;
  u16* VTb  = Kb + NE;                          // ws total ~41.3 MB
  u16* O0   = (u16*)d_out;                      // d_out as scratch: partials 0,1
  u16* O1   = O0 + NE;
  float* Lp = (float*)Wqb;                      // 768 KB; Wqb dead after gemm_qkv
  u16* Ob   = Qb;                               // combined out reuses Qb

  const float LOG2E = 1.4426950408889634f;

  hipMemsetAsync(flag, 0, 8, stream);
  mask_detect<<<32, 256, 0, stream>>>(mask, flag);
  mask_bits<<<32768, 256, 0, stream>>>(mask, mpk, flag);
  conv_w<<<dim3(512, 1, 4), 256, 0, stream>>>(Wq, Wk, Wv, Wo, Wqb, Wkb, Wvb, Wob);

  gemm_qkv<<<dim3(256, 1, 3), 256, 0, stream>>>(
      q, k, v, Wqb, Wkb, Wvb, Qb, Kb, VTb, 0.125f * LOG2E);

  flash12<<<1536, 256, 0, stream>>>(Qb, Kb, VTb, mpk, O0, O1, O2, Lp);
  combine<<<2048, 256, 0, stream>>>(O0, O1, O2, Lp, Ob);

  gemm_o<<<dim3(256), 256, 0, stream>>>(Ob, Wob, (float*)d_out);
}

// Round 16
// 154.792 us; speedup vs baseline: 1.1003x; 1.0146x over previous
//
#include <hip/hip_runtime.h>

typedef unsigned short u16;
typedef unsigned int   u32;
typedef unsigned char  u8;
typedef unsigned long long u64;
typedef __attribute__((ext_vector_type(8))) short bf16x8;
typedef __attribute__((ext_vector_type(4))) float f32x4;
typedef __attribute__((ext_vector_type(16))) float f32x16;

// fp32 -> bf16 (round-nearest-even), bit trick
__device__ __forceinline__ u16 f2b(float f) {
  union { float f; u32 u; } v; v.f = f;
  u32 u = v.u;
  return (u16)((u + 0x7fffu + ((u >> 16) & 1u)) >> 16);
}
__device__ __forceinline__ float b2f(u16 x) {
  union { u32 u; float f; } v; v.u = ((u32)x) << 16; return v.f;
}
__device__ __forceinline__ u32 pk2(u16 lo, u16 hi) { return (u32)lo | ((u32)hi << 16); }

// 2^x via v_exp_f32
__device__ __forceinline__ float fexp2(float x) { return __builtin_amdgcn_exp2f(x); }

// pack 2 f32 -> 2 bf16 in one instruction (RNE)
__device__ __forceinline__ u32 cvtpk(float lo, float hi) {
  u32 r;
  asm("v_cvt_pk_bf16_f32 %0, %1, %2" : "=v"(r) : "v"(lo), "v"(hi));
  return r;
}

// v_permlane32_swap_b32: a.hi32lanes <-> b.lo32lanes
__device__ __forceinline__ void swap32(u32& a, u32& b) {
  asm("v_permlane32_swap_b32 %0, %1" : "+v"(a), "+v"(b));
}

// async global->LDS, 16B per lane; LDS dest = wave-uniform base + lane*16
__device__ __forceinline__ void glds16(const u16* g, u16* l) {
  __builtin_amdgcn_global_load_lds((const __attribute__((address_space(1))) void*)g,
                                   (__attribute__((address_space(3))) void*)l, 16, 0, 0);
}

// ---------------------------------------------------------------------------
// Mask dtype detection (parallel): flag[0]!=0 -> bool; else flag[1]!=0 -> f32
// ---------------------------------------------------------------------------
__global__ __launch_bounds__(256) void mask_detect(const u8* __restrict__ raw,
                                                   int* __restrict__ flag) {
  int i = blockIdx.x * 256 + threadIdx.x;
  uint4 x = ((const uint4*)raw)[i];
  u32 o = x.x | x.y | x.z | x.w;
  u64 b1 = __ballot((o & 0x0000ff00u) != 0);
  u64 b2 = __ballot((o & 0xffff0000u) != 0);
  if ((threadIdx.x & 63) == 0) {
    if (b1) atomicOr(&flag[0], 1);
    if (b2) atomicOr(&flag[1], 1);
  }
}

// Bitpack mask: out[i>>6] bit (i&63) = mask element i != 0
__global__ __launch_bounds__(256) void mask_bits(const u8* __restrict__ raw,
                                                 u64* __restrict__ out,
                                                 const int* __restrict__ flag) {
  int f = flag[0] ? 2 : (flag[1] ? 1 : 0);
  int i = blockIdx.x * 256 + threadIdx.x;
  bool bit;
  if (f == 2)      bit = raw[i] != 0;
  else if (f == 0) bit = ((const int*)raw)[i] != 0;
  else             bit = ((const float*)raw)[i] != 0.0f;
  u64 b = __ballot(bit);
  if ((threadIdx.x & 63) == 0) out[i >> 6] = b;
}

// ---------------------------------------------------------------------------
// Convert 4 weight matrices fp32 -> bf16 (1M elems each)
// ---------------------------------------------------------------------------
__global__ __launch_bounds__(256) void conv_w(const float* __restrict__ W0, const float* __restrict__ W1,
                                              const float* __restrict__ W2, const float* __restrict__ W3,
                                              u16* __restrict__ o0, u16* __restrict__ o1,
                                              u16* __restrict__ o2, u16* __restrict__ o3) {
  int zz = blockIdx.z;
  const float* W = zz == 0 ? W0 : zz == 1 ? W1 : zz == 2 ? W2 : W3;
  u16* o = zz == 0 ? o0 : zz == 1 ? o1 : zz == 2 ? o2 : o3;
  int i = (blockIdx.x * 256 + threadIdx.x) * 8;
  float4 a = *(const float4*)(W + i), b2 = *(const float4*)(W + i + 4);
  uint4 t;
  t.x = pk2(f2b(a.x), f2b(a.y));   t.y = pk2(f2b(a.z), f2b(a.w));
  t.z = pk2(f2b(b2.x), f2b(b2.y)); t.w = pk2(f2b(b2.z), f2b(b2.w));
  *(uint4*)(o + i) = t;
}

// ---------------------------------------------------------------------------
// NT GEMM body, 128x64 tile: C[m][n] = cscale * sum_k A[m][k]*B[n][k]
// 4 waves of 32x64 (acc[2][4], 16 MFMA/K-step), BK=64, single-buffered LDS
// (24 KB -> 6 blocks/CU), 2 barriers/K-step (m97 structure, TLP-covered).
// AF32/BF32: operand fp32 in global, reg-staged (issue float4 under MFMA,
// cvtpk + swizzled ds_write at staging point). bf16 operands: glds16.
// ---------------------------------------------------------------------------
template<int AF32, int BF32, int CF32>
__device__ __forceinline__ void gemm64_body(
    const void* __restrict__ Av, const void* __restrict__ Bv, void* __restrict__ Cv,
    int N, int K, int m0, int n0, float cscale, u16* As, u16* Bs) {
  const int tid = threadIdx.x;
  const int lane = tid & 63, w = tid >> 6;
  const int lr = lane & 15, lg = lane >> 4;
  const int wm = w * 32;                       // wave's row quadrant (32 rows)
  const int srow = lane >> 3;
  const int selem = (((lane & 7) ^ srow) << 3);
  const int rsw = (lr & 7) << 3;

  f32x4 acc[2][4];
#pragma unroll
  for (int mi = 0; mi < 2; ++mi)
#pragma unroll
    for (int ni = 0; ni < 4; ++ni)
      acc[mi][ni] = (f32x4){0.f, 0.f, 0.f, 0.f};

  float4 fa0[4], fa1[4], fb0[2], fb1[2];

  // A: 128x64 u16 = 16 chunks (4/wave); B: 64x64 u16 = 8 chunks (2/wave)
#define GLDS_A(P, k0_)                                                         \
  do {                                                                         \
    _Pragma("unroll")                                                          \
    for (int r_ = 0; r_ < 4; ++r_) {                                           \
      const int c_ = w * 4 + r_;                                               \
      const int row_ = c_ * 8 + srow;                                          \
      glds16((const u16*)(P) + (size_t)(m0 + row_) * K + (k0_) + selem, As + c_ * 512); \
    }                                                                          \
  } while (0)
#define GLDS_B(P, k0_)                                                         \
  do {                                                                         \
    _Pragma("unroll")                                                          \
    for (int r_ = 0; r_ < 2; ++r_) {                                           \
      const int c_ = w * 2 + r_;                                               \
      const int row_ = c_ * 8 + srow;                                          \
      glds16((const u16*)(P) + (size_t)(n0 + row_) * K + (k0_) + selem, Bs + c_ * 512); \
    }                                                                          \
  } while (0)
#define F32_ISSUE(P, base, k0_, f0, f1, NC)                                    \
  do {                                                                         \
    _Pragma("unroll")                                                          \
    for (int rr = 0; rr < (NC); ++rr) {                                        \
      const int ch_ = rr * 256 + tid;                                          \
      const int row_ = ch_ >> 3, col_ = (ch_ & 7) * 8;                         \
      const float* p_ = (const float*)(P) + (size_t)((base) + row_) * K + (k0_) + col_; \
      f0[rr] = *(const float4*)p_;                                             \
      f1[rr] = *(const float4*)(p_ + 4);                                       \
    }                                                                          \
  } while (0)
#define F32_WRITE(LB, f0, f1, NC)                                              \
  do {                                                                         \
    _Pragma("unroll")                                                          \
    for (int rr = 0; rr < (NC); ++rr) {                                        \
      const int ch_ = rr * 256 + tid;                                          \
      const int row_ = ch_ >> 3, col_ = (ch_ & 7) * 8;                         \
      uint4 t_;                                                                \
      t_.x = cvtpk(f0[rr].x, f0[rr].y); t_.y = cvtpk(f0[rr].z, f0[rr].w);      \
      t_.z = cvtpk(f1[rr].x, f1[rr].y); t_.w = cvtpk(f1[rr].z, f1[rr].w);      \
      *(uint4*)&(LB)[row_ * 64 + (col_ ^ ((row_ & 7) << 3))] = t_;             \
    }                                                                          \
  } while (0)

  if (AF32) F32_ISSUE(Av, m0, 0, fa0, fa1, 4);
  if (BF32) F32_ISSUE(Bv, n0, 0, fb0, fb1, 2);
  for (int k0 = 0; k0 < K; k0 += 64) {
    const bool nx = (k0 + 64 < K);
    __syncthreads();   // all waves done reading previous tile
    if (AF32) F32_WRITE(As, fa0, fa1, 4);
    else      GLDS_A(Av, k0);
    if (BF32) F32_WRITE(Bs, fb0, fb1, 2);
    else      GLDS_B(Bv, k0);
    __syncthreads();   // staging drained
    if (nx) {          // next tile's fp32 loads fly across the MFMAs
      if (AF32) F32_ISSUE(Av, m0, k0 + 64, fa0, fa1, 4);
      if (BF32) F32_ISSUE(Bv, n0, k0 + 64, fb0, fb1, 2);
    }
    bf16x8 af[2][2], bfv[4][2];
#pragma unroll
    for (int mi = 0; mi < 2; ++mi)
#pragma unroll
      for (int kk = 0; kk < 2; ++kk)
        af[mi][kk] = *(bf16x8*)&As[(wm + mi * 16 + lr) * 64 + ((kk * 32 + lg * 8) ^ rsw)];
#pragma unroll
    for (int ni = 0; ni < 4; ++ni)
#pragma unroll
      for (int kk = 0; kk < 2; ++kk)
        bfv[ni][kk] = *(bf16x8*)&Bs[(ni * 16 + lr) * 64 + ((kk * 32 + lg * 8) ^ rsw)];
    __builtin_amdgcn_s_setprio(1);
#pragma unroll
    for (int mi = 0; mi < 2; ++mi)
#pragma unroll
      for (int ni = 0; ni < 4; ++ni)
#pragma unroll
        for (int kk = 0; kk < 2; ++kk)
          acc[mi][ni] = __builtin_amdgcn_mfma_f32_16x16x32_bf16(
              af[mi][kk], bfv[ni][kk], acc[mi][ni], 0, 0, 0);
    __builtin_amdgcn_s_setprio(0);
  }
#undef GLDS_A
#undef GLDS_B
#undef F32_ISSUE
#undef F32_WRITE
#pragma unroll
  for (int mi = 0; mi < 2; ++mi)
#pragma unroll
    for (int ni = 0; ni < 4; ++ni)
#pragma unroll
      for (int r = 0; r < 4; ++r) {
        int m = m0 + wm + mi * 16 + lg * 4 + r;
        int n = n0 + ni * 16 + lr;
        float vv = acc[mi][ni][r] * cscale;
        if (CF32) ((float*)Cv)[(size_t)m * N + n] = vv;
        else      ((u16*)Cv)[(size_t)m * N + n] = f2b(vv);
      }
}

// Fused Q,K,V projections from fp32 activations, 128x64 tiles, XCD-swizzled
// (blocks sharing one fp32 panel co-resident on one XCD -> L2-served).
// z=0 Q (scaled), z=1 K, z=2 V-transposed. grid.x = 512 each.
__global__ __launch_bounds__(256) void gemm_qkv(
    const float* __restrict__ q, const float* __restrict__ k, const float* __restrict__ v,
    const u16* __restrict__ Wqb, const u16* __restrict__ Wkb, const u16* __restrict__ Wvb,
    u16* __restrict__ Qb, u16* __restrict__ Kb, u16* __restrict__ VTb, float qscale) {
  __shared__ __align__(16) u16 As[128 * 64];
  __shared__ __align__(16) u16 Bs[64 * 64];
  const int z = blockIdx.z;
  const int xcd = blockIdx.x & 7, r = blockIdx.x >> 3;   // r 0..63
  if (z < 2) {
    // A = acts fp32 [4096x1024] (m-panels of 128: 32, 4/XCD); B = weights bf16
    const int pblk = xcd * 4 + (r & 3);                  // 0..31
    const int oblk = r >> 2;                             // 0..15 (64-col blocks)
    const float* act = z ? k : q;
    const u16* Wb = z ? Wkb : Wqb;
    u16* Cb = z ? Kb : Qb;
    gemm64_body<1, 0, 0>(act, Wb, Cb, 1024, 1024, pblk * 128, oblk * 64,
                         z ? 1.0f : qscale, As, Bs);
  } else {
    // VT = Wv . v^T: A = Wv bf16 (8 m-blocks); B = v fp32 (n-panels of 64: 64, 8/XCD)
    const int pblk = xcd * 8 + (r & 7);                  // 0..63
    const int oblk = r >> 3;                             // 0..7
    gemm64_body<0, 1, 0>(Wvb, v, VTb, 4096, 1024, oblk * 128, pblk * 64,
                         1.0f, As, Bs);
  }
}

// Output projection -> fp32, 128x64 tiles, XCD-swizzled. grid = 512 (2/CU).
__global__ __launch_bounds__(256) void gemm_o(
    const u16* __restrict__ Ob, const u16* __restrict__ Wob, float* __restrict__ C) {
  __shared__ __align__(16) u16 As[128 * 64];
  __shared__ __align__(16) u16 Bs[64 * 64];
  const int xcd = blockIdx.x & 7, r = blockIdx.x >> 3;   // r 0..63
  const int mblk = xcd * 4 + (r & 3), nblk = r >> 2;     // 32 x 16
  gemm64_body<0, 0, 1>(Ob, Wob, C, 1024, 1024, mblk * 128, nblk * 64, 1.0f, As, Bs);
}

// ---------------------------------------------------------------------------
// Flash attention v12 (proven): K-split x3, tile ranges {0..10,10..21,21..32},
// additive partials (no max-tracking), 32x32 swapped QK^T + permlane32_swap,
// row-sums via ones-MFMA, double-buffered LDS. grid = 1536, 256 thr.
// ---------------------------------------------------------------------------
__global__ __launch_bounds__(256, 4) void flash12(const u16* __restrict__ Q,
                                                  const u16* __restrict__ K,
                                                  const u16* __restrict__ VT,
                                                  const u64* __restrict__ mpk,
                                                  u16* __restrict__ O0,
                                                  u16* __restrict__ O1,
                                                  u16* __restrict__ O2,
                                                  float* __restrict__ Lp) {
  __shared__ __align__(16) u16 Ks[2][4096];   // [64 key][64 d], swizzled
  __shared__ __align__(16) u16 Vs[2][4096];   // [64 d][64 key], swizzled
  const int tid = threadIdx.x, lane = tid & 63, w = tid >> 6;
  const int c = lane & 31, h = lane >> 5;
  const int bid = blockIdx.x;
  const int xcd = bid & 7, idx = bid >> 3;        // idx 0..191
  const int gl = idx >> 4, qblk = idx & 15;       // gl 0..11
  const int group = xcd * 12 + gl;                // 0..95
  const int split = group % 3;
  const int hb = group / 3;                       // 0..31
  const int head = hb & 15, b = hb >> 4;
  const int qw = qblk * 128 + w * 32;
  const int kt0 = (split * 32) / 3;               // 0, 10, 21
  const int ktn = ((split + 1) * 32) / 3;         // 10, 21, 32
  const int nt = ktn - kt0;
  const size_t kbase = (size_t)b * 2048 * 1024 + (size_t)head * 64;
  const size_t vbase = (size_t)head * 64 * 4096 + (size_t)b * 2048;
  const int srow = lane >> 3;
  const int selem = (((lane & 7) ^ srow) << 3);
  const int rswc = (c & 7) << 3;

  bf16x8 qf[4];
#pragma unroll
  for (int kd = 0; kd < 4; ++kd)
    qf[kd] = *(const bf16x8*)&Q[kbase + (size_t)(qw + c) * 1024 + 16 * kd + 8 * h];

  union { u32 u[4]; bf16x8 v; } ones;
#pragma unroll
  for (int i = 0; i < 4; ++i) ones.u[i] = 0x3f803f80u;

  f32x16 accO0, accO1, accL;
#pragma unroll
  for (int i = 0; i < 16; ++i) { accO0[i] = 0.f; accO1[i] = 0.f; accL[i] = 0.f; }

  const u64* mrp = mpk + ((size_t)b * 2048 + qw + c) * 32;

#define STAGE(buf, t)                                                          \
  do {                                                                         \
    const int k0_ = (t) * 64;                                                  \
    _Pragma("unroll")                                                          \
    for (int r_ = 0; r_ < 2; ++r_) {                                           \
      const int c_ = w * 2 + r_;                                               \
      const int row_ = c_ * 8 + srow;                                          \
      glds16(K + kbase + (size_t)(k0_ + row_) * 1024 + selem, &Ks[buf][c_ * 512]); \
    }                                                                          \
    _Pragma("unroll")                                                          \
    for (int r_ = 0; r_ < 2; ++r_) {                                           \
      const int c_ = w * 2 + r_;                                               \
      const int row_ = c_ * 8 + srow;                                          \
      glds16(VT + vbase + (size_t)row_ * 4096 + k0_ + selem, &Vs[buf][c_ * 512]); \
    }                                                                          \
  } while (0)

  STAGE(0, kt0);
  u64 mb_next = mrp[kt0];
  __syncthreads();

  int cur = 0;
  for (int t = 0; t < nt; ++t) {
    const u64 mb = mb_next;
    if (t + 1 < nt) {
      STAGE(cur ^ 1, kt0 + t + 1);
      mb_next = mrp[kt0 + t + 1];
    }
    const u16* ks = Ks[cur];
    const u16* vs = Vs[cur];
    f32x16 s0, s1;
#pragma unroll
    for (int i = 0; i < 16; ++i) { s0[i] = 0.f; s1[i] = 0.f; }
    __builtin_amdgcn_s_setprio(1);
#pragma unroll
    for (int kd = 0; kd < 4; ++kd) {
      bf16x8 kf0 = *(bf16x8*)&ks[c * 64 + ((16 * kd + 8 * h) ^ rswc)];
      s0 = __builtin_amdgcn_mfma_f32_32x32x16_bf16(kf0, qf[kd], s0, 0, 0, 0);
      bf16x8 kf1 = *(bf16x8*)&ks[(32 + c) * 64 + ((16 * kd + 8 * h) ^ rswc)];
      s1 = __builtin_amdgcn_mfma_f32_32x32x16_bf16(kf1, qf[kd], s1, 0, 0, 0);
    }
    __builtin_amdgcn_s_setprio(0);
    u32 pw[2][4][2];
#pragma unroll
    for (int kb = 0; kb < 2; ++kb) {
      const u32 m32 = (u32)(mb >> (32 * kb + 4 * h));
      float pp[16];
#pragma unroll
      for (int g = 0; g < 4; ++g)
#pragma unroll
        for (int r = 0; r < 4; ++r) {
          float e = fexp2(kb == 0 ? s0[4 * g + r] : s1[4 * g + r]);
          pp[4 * g + r] = ((m32 >> (8 * g + r)) & 1) ? 0.0f : e;
        }
#pragma unroll
      for (int g = 0; g < 4; ++g)
#pragma unroll
        for (int hh = 0; hh < 2; ++hh)
          pw[kb][g][hh] = cvtpk(pp[4 * g + 2 * hh], pp[4 * g + 2 * hh + 1]);
    }
    __builtin_amdgcn_s_setprio(1);
#pragma unroll
    for (int kb = 0; kb < 2; ++kb)
#pragma unroll
      for (int s = 0; s < 2; ++s) {
        u32 w0 = pw[kb][2 * s][0], w2 = pw[kb][2 * s + 1][0];
        swap32(w0, w2);
        u32 w1 = pw[kb][2 * s][1], w3 = pw[kb][2 * s + 1][1];
        swap32(w1, w3);
        union { u32 u[4]; bf16x8 v; } af;
        af.u[0] = w0; af.u[1] = w1; af.u[2] = w2; af.u[3] = w3;
        const int ksg = kb * 2 + s;
        bf16x8 vf0 = *(bf16x8*)&vs[c * 64 + ((16 * ksg + 8 * h) ^ rswc)];
        accO0 = __builtin_amdgcn_mfma_f32_32x32x16_bf16(af.v, vf0, accO0, 0, 0, 0);
        bf16x8 vf1 = *(bf16x8*)&vs[(32 + c) * 64 + ((16 * ksg + 8 * h) ^ rswc)];
        accO1 = __builtin_amdgcn_mfma_f32_32x32x16_bf16(af.v, vf1, accO1, 0, 0, 0);
        accL  = __builtin_amdgcn_mfma_f32_32x32x16_bf16(af.v, ones.v, accL, 0, 0, 0);
      }
    __builtin_amdgcn_s_setprio(0);
    __syncthreads();
    cur ^= 1;
  }
#undef STAGE
  u16* Op = split == 0 ? O0 : split == 1 ? O1 : O2;
  const size_t obase = (size_t)b * 2048 + qw;
#pragma unroll
  for (int g = 0; g < 4; ++g)
#pragma unroll
    for (int r = 0; r < 4; ++r) {
      const int qrow = r + 8 * g + 4 * h;
      const size_t row = obase + qrow;
      const size_t base = row * 1024 + (size_t)head * 64 + c;
      Op[base]      = f2b(accO0[4 * g + r]);
      Op[base + 32] = f2b(accO1[4 * g + r]);
      if (c == 0) Lp[(size_t)split * 65536 + row * 16 + head] = accL[4 * g + r];
    }
}

// ---------------------------------------------------------------------------
// Combine 3 K-split partials: O = (O0+O1+O2) / (L0+L1+L2), bf16 out
// ---------------------------------------------------------------------------
__global__ __launch_bounds__(256) void combine(const u16* __restrict__ O0,
                                               const u16* __restrict__ O1,
                                               const u16* __restrict__ O2,
                                               const float* __restrict__ Lp,
                                               u16* __restrict__ Ob) {
  int gid = blockIdx.x * 256 + threadIdx.x;
  int row = gid >> 7, chb = (gid & 127) * 8;
  int head = chb >> 6;
  float l = Lp[(size_t)row * 16 + head] + Lp[65536 + (size_t)row * 16 + head] +
            Lp[131072 + (size_t)row * 16 + head];
  float inv = 1.0f / l;
  size_t off = (size_t)row * 1024 + chb;
  union { uint4 q; u16 s[8]; } a, b, c2, o;
  a.q  = *(const uint4*)(O0 + off);
  b.q  = *(const uint4*)(O1 + off);
  c2.q = *(const uint4*)(O2 + off);
#pragma unroll
  for (int j = 0; j < 8; ++j)
    o.s[j] = f2b((b2f(a.s[j]) + b2f(b.s[j]) + b2f(c2.s[j])) * inv);
  *(uint4*)(Ob + off) = o.q;
}

// ---------------------------------------------------------------------------
extern "C" void kernel_launch(void* const* d_in, const int* in_sizes, int n_in,
                              void* d_out, int out_size, void* d_ws, size_t ws_size,
                              hipStream_t stream) {
  const float* q    = (const float*)d_in[0];
  const float* k    = (const float*)d_in[1];
  const float* v    = (const float*)d_in[2];
  const u8*    mask = (const u8*)d_in[3];
  const float* Wq   = (const float*)d_in[4];
  const float* Wk   = (const float*)d_in[5];
  const float* Wv   = (const float*)d_in[6];
  const float* Wo   = (const float*)d_in[7];

  u8* ws = (u8*)d_ws;
  int* flag = (int*)ws;                         // 256 B
  u64* mpk  = (u64*)(ws + 256);                 // 1 MB
  u16* Wqb  = (u16*)(ws + 256 + (1u << 20));    // 2 MB each
  u16* Wkb  = Wqb + (1 << 20);
  u16* Wvb  = Wkb + (1 << 20);
  u16* Wob  = Wvb + (1 << 20);
  const size_t NE = (size_t)4096 * 1024;
  u16* O2   = Wob + (1 << 20);                  // 8 MB: split-2 partial
  u16* Qb   = O2 + NE;                          // 8 MB each
  u16* Kb   = Qb + NE;
  u16* VTb  = Kb + NE;                          // ws total ~41.3 MB
  u16* O0   = (u16*)d_out;                      // d_out as scratch: partials 0,1
  u16* O1   = O0 + NE;
  float* Lp = (float*)Wqb;                      // 768 KB; Wqb dead after gemm_qkv
  u16* Ob   = Qb;                               // combined out reuses Qb

  const float LOG2E = 1.4426950408889634f;

  hipMemsetAsync(flag, 0, 8, stream);
  mask_detect<<<32, 256, 0, stream>>>(mask, flag);
  mask_bits<<<32768, 256, 0, stream>>>(mask, mpk, flag);
  conv_w<<<dim3(512, 1, 4), 256, 0, stream>>>(Wq, Wk, Wv, Wo, Wqb, Wkb, Wvb, Wob);

  gemm_qkv<<<dim3(512, 1, 3), 256, 0, stream>>>(
      q, k, v, Wqb, Wkb, Wvb, Qb, Kb, VTb, 0.125f * LOG2E);

  flash12<<<1536, 256, 0, stream>>>(Qb, Kb, VTb, mpk, O0, O1, O2, Lp);
  combine<<<2048, 256, 0, stream>>>(O0, O1, O2, Lp, Ob);

  gemm_o<<<512, 256, 0, stream>>>(Ob, Wob, (float*)d_out);
}

// Round 17
// 142.676 us; speedup vs baseline: 1.1937x; 1.0849x over previous
//
#include <hip/hip_runtime.h>

typedef unsigned short u16;
typedef unsigned int   u32;
typedef unsigned char  u8;
typedef unsigned long long u64;
typedef __attribute__((ext_vector_type(8))) short bf16x8;
typedef __attribute__((ext_vector_type(4))) float f32x4;
typedef __attribute__((ext_vector_type(16))) float f32x16;

// fp32 -> bf16 (round-nearest-even), bit trick
__device__ __forceinline__ u16 f2b(float f) {
  union { float f; u32 u; } v; v.f = f;
  u32 u = v.u;
  return (u16)((u + 0x7fffu + ((u >> 16) & 1u)) >> 16);
}
__device__ __forceinline__ float b2f(u16 x) {
  union { u32 u; float f; } v; v.u = ((u32)x) << 16; return v.f;
}
__device__ __forceinline__ u32 pk2(u16 lo, u16 hi) { return (u32)lo | ((u32)hi << 16); }

// 2^x via v_exp_f32
__device__ __forceinline__ float fexp2(float x) { return __builtin_amdgcn_exp2f(x); }

// pack 2 f32 -> 2 bf16 in one instruction (RNE)
__device__ __forceinline__ u32 cvtpk(float lo, float hi) {
  u32 r;
  asm("v_cvt_pk_bf16_f32 %0, %1, %2" : "=v"(r) : "v"(lo), "v"(hi));
  return r;
}

// v_permlane32_swap_b32: a.hi32lanes <-> b.lo32lanes
__device__ __forceinline__ void swap32(u32& a, u32& b) {
  asm("v_permlane32_swap_b32 %0, %1" : "+v"(a), "+v"(b));
}

// async global->LDS, 16B per lane; LDS dest = wave-uniform base + lane*16
__device__ __forceinline__ void glds16(const u16* g, u16* l) {
  __builtin_amdgcn_global_load_lds((const __attribute__((address_space(1))) void*)g,
                                   (__attribute__((address_space(3))) void*)l, 16, 0, 0);
}

// ---------------------------------------------------------------------------
// Mask dtype detection (parallel): flag[0]!=0 -> bool; else flag[1]!=0 -> f32
// ---------------------------------------------------------------------------
__global__ __launch_bounds__(256) void mask_detect(const u8* __restrict__ raw,
                                                   int* __restrict__ flag) {
  int i = blockIdx.x * 256 + threadIdx.x;
  uint4 x = ((const uint4*)raw)[i];
  u32 o = x.x | x.y | x.z | x.w;
  u64 b1 = __ballot((o & 0x0000ff00u) != 0);
  u64 b2 = __ballot((o & 0xffff0000u) != 0);
  if ((threadIdx.x & 63) == 0) {
    if (b1) atomicOr(&flag[0], 1);
    if (b2) atomicOr(&flag[1], 1);
  }
}

// Bitpack mask, vectorized: thread t packs elements 8t..8t+7 into byte t.
// bit j of output word w = element 64w + j  (same mapping as before).
__global__ __launch_bounds__(256) void mask_bits(const u8* __restrict__ raw,
                                                 u64* __restrict__ out,
                                                 const int* __restrict__ flag) {
  int f = flag[0] ? 2 : (flag[1] ? 1 : 0);
  int t = blockIdx.x * 256 + threadIdx.x;   // 4096 blocks x 256 = 1M threads
  u8 byte;
  if (f == 2) {
    u64 x = ((const u64*)raw)[t];
    u64 nz = x | (x >> 4); nz |= nz >> 2; nz |= nz >> 1;
    nz &= 0x0101010101010101ull;
    byte = (u8)((nz * 0x0102040810204080ull) >> 56);
  } else if (f == 0) {
    const int* ip = (const int*)raw + t * 8;
    int4 a = *(const int4*)ip, b = *(const int4*)(ip + 4);
    byte = (u8)((a.x != 0) | ((a.y != 0) << 1) | ((a.z != 0) << 2) | ((a.w != 0) << 3) |
                ((b.x != 0) << 4) | ((b.y != 0) << 5) | ((b.z != 0) << 6) | ((b.w != 0) << 7));
  } else {
    const float* fp = (const float*)raw + t * 8;
    float4 a = *(const float4*)fp, b = *(const float4*)(fp + 4);
    byte = (u8)((a.x != 0.f) | ((a.y != 0.f) << 1) | ((a.z != 0.f) << 2) | ((a.w != 0.f) << 3) |
                ((b.x != 0.f) << 4) | ((b.y != 0.f) << 5) | ((b.z != 0.f) << 6) | ((b.w != 0.f) << 7));
  }
  ((u8*)out)[t] = byte;
}

// ---------------------------------------------------------------------------
// Fused fp32->bf16 conversion: 4 weights (1M elems each) + 3 acts (4M each)
// ---------------------------------------------------------------------------
__global__ __launch_bounds__(256) void conv_all(
    const float* __restrict__ W0, const float* __restrict__ W1,
    const float* __restrict__ W2, const float* __restrict__ W3,
    const float* __restrict__ A0, const float* __restrict__ A1,
    const float* __restrict__ A2,
    u16* __restrict__ o0, u16* __restrict__ o1, u16* __restrict__ o2,
    u16* __restrict__ o3, u16* __restrict__ o4, u16* __restrict__ o5,
    u16* __restrict__ o6) {
  int gid = blockIdx.x * 256 + threadIdx.x;
  const float* src; u16* dst; int off;
  if (gid < 524288) {
    int wz = gid >> 17; off = (gid & 131071) * 8;
    src = wz == 0 ? W0 : wz == 1 ? W1 : wz == 2 ? W2 : W3;
    dst = wz == 0 ? o0 : wz == 1 ? o1 : wz == 2 ? o2 : o3;
  } else {
    int g2 = gid - 524288;
    int az = g2 >> 19; off = (g2 & 524287) * 8;
    src = az == 0 ? A0 : az == 1 ? A1 : A2;
    dst = az == 0 ? o4 : az == 1 ? o5 : o6;
  }
  float4 a = *(const float4*)(src + off), b2 = *(const float4*)(src + off + 4);
  uint4 t;
  t.x = pk2(f2b(a.x), f2b(a.y));   t.y = pk2(f2b(a.z), f2b(a.w));
  t.z = pk2(f2b(b2.x), f2b(b2.y)); t.w = pk2(f2b(b2.z), f2b(b2.w));
  *(uint4*)(dst + off) = t;
}

// ---------------------------------------------------------------------------
// NT GEMM body, 128x128 tile, all-bf16 glds16 staging, T2 swizzle.
// DBUF=0: single-buffered LDS (32 KB -> 5 blocks/CU), 2 barriers/K-step
//   (m97 structure; async DMA staging, latency covered by block TLP).
// DBUF=1: double-buffered (for 1-block/CU grids).
// ---------------------------------------------------------------------------
template<int CF32, int DBUF>
__device__ __forceinline__ void gemm_body(
    const u16* __restrict__ Av, const u16* __restrict__ Bv, void* __restrict__ Cv,
    int N, int K, int m0, int n0, float cscale, u16* As, u16* Bs) {
  const int tid = threadIdx.x;
  const int lane = tid & 63, w = tid >> 6;
  const int lr = lane & 15, lg = lane >> 4;
  const int wm = (w >> 1) * 64, wn = (w & 1) * 64;
  const int srow = lane >> 3;
  const int selem = (((lane & 7) ^ srow) << 3);
  const int rsw = (lr & 7) << 3;

  f32x4 acc[4][4];
#pragma unroll
  for (int mi = 0; mi < 4; ++mi)
#pragma unroll
    for (int ni = 0; ni < 4; ++ni)
      acc[mi][ni] = (f32x4){0.f, 0.f, 0.f, 0.f};

#define GLDS2(k0_, LA, LB)                                                     \
  do {                                                                         \
    _Pragma("unroll")                                                          \
    for (int r_ = 0; r_ < 4; ++r_) {                                           \
      const int c_ = w * 4 + r_;                                               \
      const int row_ = c_ * 8 + srow;                                          \
      glds16(Av + (size_t)(m0 + row_) * K + (k0_) + selem, (LA) + c_ * 512);   \
      glds16(Bv + (size_t)(n0 + row_) * K + (k0_) + selem, (LB) + c_ * 512);   \
    }                                                                          \
  } while (0)

#define FRAG_MFMA(bufA, bufB)                                                  \
  do {                                                                         \
    bf16x8 af[4][2], bfv[4][2];                                                \
    _Pragma("unroll")                                                          \
    for (int mi = 0; mi < 4; ++mi)                                             \
      _Pragma("unroll")                                                        \
      for (int kk = 0; kk < 2; ++kk)                                           \
        af[mi][kk] = *(bf16x8*)&(bufA)[(wm + mi * 16 + lr) * 64 + ((kk * 32 + lg * 8) ^ rsw)]; \
    _Pragma("unroll")                                                          \
    for (int ni = 0; ni < 4; ++ni)                                             \
      _Pragma("unroll")                                                        \
      for (int kk = 0; kk < 2; ++kk)                                           \
        bfv[ni][kk] = *(bf16x8*)&(bufB)[(wn + ni * 16 + lr) * 64 + ((kk * 32 + lg * 8) ^ rsw)]; \
    __builtin_amdgcn_s_setprio(1);                                             \
    _Pragma("unroll")                                                          \
    for (int mi = 0; mi < 4; ++mi)                                             \
      _Pragma("unroll")                                                        \
      for (int ni = 0; ni < 4; ++ni)                                           \
        _Pragma("unroll")                                                      \
        for (int kk = 0; kk < 2; ++kk)                                         \
          acc[mi][ni] = __builtin_amdgcn_mfma_f32_16x16x32_bf16(               \
              af[mi][kk], bfv[ni][kk], acc[mi][ni], 0, 0, 0);                  \
    __builtin_amdgcn_s_setprio(0);                                             \
  } while (0)

  if (DBUF) {
    GLDS2(0, As, Bs);
    __syncthreads();
    int cur = 0;
    for (int k0 = 0; k0 < K; k0 += 64) {
      if (k0 + 64 < K) GLDS2(k0 + 64, As + (cur ^ 1) * 8192, Bs + (cur ^ 1) * 8192);
      FRAG_MFMA(As + cur * 8192, Bs + cur * 8192);
      __syncthreads();
      cur ^= 1;
    }
  } else {
    for (int k0 = 0; k0 < K; k0 += 64) {
      __syncthreads();        // all waves done reading the previous tile
      GLDS2(k0, As, Bs);
      __syncthreads();        // staging drained (vmcnt0)
      FRAG_MFMA(As, Bs);
    }
  }
#undef GLDS2
#undef FRAG_MFMA
#pragma unroll
  for (int mi = 0; mi < 4; ++mi)
#pragma unroll
    for (int ni = 0; ni < 4; ++ni)
#pragma unroll
      for (int r = 0; r < 4; ++r) {
        int m = m0 + wm + mi * 16 + lg * 4 + r;
        int n = n0 + wn + ni * 16 + lr;
        float vv = acc[mi][ni][r] * cscale;
        if (CF32) ((float*)Cv)[(size_t)m * N + n] = vv;
        else      ((u16*)Cv)[(size_t)m * N + n] = f2b(vv);
      }
}

// Fused Q,K,V projections, all-bf16 (pre-converted acts), m97 single-buffer.
// XCD-swizzled: 8 blocks sharing one act panel co-resident on one XCD.
// z=0 Q (scaled), z=1 K, z=2 V-transposed. grid (256,1,3).
__global__ __launch_bounds__(256) void gemm_qkv(
    const u16* __restrict__ qb, const u16* __restrict__ kb, const u16* __restrict__ vb,
    const u16* __restrict__ Wqb, const u16* __restrict__ Wkb, const u16* __restrict__ Wvb,
    u16* __restrict__ Qb, u16* __restrict__ Kb, u16* __restrict__ VTb, float qscale) {
  __shared__ __align__(16) u16 As[8192];
  __shared__ __align__(16) u16 Bs[8192];
  const int z = blockIdx.z;
  const int xcd = blockIdx.x & 7, r = blockIdx.x >> 3;   // bijective: 8*4*8=256
  const int pblk = xcd * 4 + (r & 3);                    // act panel 0..31
  const int oblk = r >> 2;                               // 0..7
  if (z < 2) {
    const u16* act = z ? kb : qb;
    const u16* Wb = z ? Wkb : Wqb;
    u16* Cb = z ? Kb : Qb;
    gemm_body<0, 0>(act, Wb, Cb, 1024, 1024, pblk * 128, oblk * 128,
                    z ? 1.0f : qscale, As, Bs);
  } else {
    // VT = Wv . v^T : A = Wv bf16 (m-blocks = oblk), B = v bf16 (n-panel = pblk)
    gemm_body<0, 0>(Wvb, vb, VTb, 4096, 1024, oblk * 128, pblk * 128, 1.0f, As, Bs);
  }
}

// ---------------------------------------------------------------------------
// Output projection -> fp32, 128x64 tiles (round-16 proven, ~13 us),
// XCD-swizzled, single-buffer 24 KB. grid = 512.
// ---------------------------------------------------------------------------
__device__ __forceinline__ void gemm64_body(
    const u16* __restrict__ Av, const u16* __restrict__ Bv, float* __restrict__ Cv,
    int N, int K, int m0, int n0, u16* As, u16* Bs) {
  const int tid = threadIdx.x;
  const int lane = tid & 63, w = tid >> 6;
  const int lr = lane & 15, lg = lane >> 4;
  const int wm = w * 32;
  const int srow = lane >> 3;
  const int selem = (((lane & 7) ^ srow) << 3);
  const int rsw = (lr & 7) << 3;

  f32x4 acc[2][4];
#pragma unroll
  for (int mi = 0; mi < 2; ++mi)
#pragma unroll
    for (int ni = 0; ni < 4; ++ni)
      acc[mi][ni] = (f32x4){0.f, 0.f, 0.f, 0.f};

  for (int k0 = 0; k0 < K; k0 += 64) {
    __syncthreads();
#pragma unroll
    for (int r_ = 0; r_ < 4; ++r_) {
      const int c_ = w * 4 + r_;
      const int row_ = c_ * 8 + srow;
      glds16(Av + (size_t)(m0 + row_) * K + k0 + selem, As + c_ * 512);
    }
#pragma unroll
    for (int r_ = 0; r_ < 2; ++r_) {
      const int c_ = w * 2 + r_;
      const int row_ = c_ * 8 + srow;
      glds16(Bv + (size_t)(n0 + row_) * K + k0 + selem, Bs + c_ * 512);
    }
    __syncthreads();
    bf16x8 af[2][2], bfv[4][2];
#pragma unroll
    for (int mi = 0; mi < 2; ++mi)
#pragma unroll
      for (int kk = 0; kk < 2; ++kk)
        af[mi][kk] = *(bf16x8*)&As[(wm + mi * 16 + lr) * 64 + ((kk * 32 + lg * 8) ^ rsw)];
#pragma unroll
    for (int ni = 0; ni < 4; ++ni)
#pragma unroll
      for (int kk = 0; kk < 2; ++kk)
        bfv[ni][kk] = *(bf16x8*)&Bs[(ni * 16 + lr) * 64 + ((kk * 32 + lg * 8) ^ rsw)];
    __builtin_amdgcn_s_setprio(1);
#pragma unroll
    for (int mi = 0; mi < 2; ++mi)
#pragma unroll
      for (int ni = 0; ni < 4; ++ni)
#pragma unroll
        for (int kk = 0; kk < 2; ++kk)
          acc[mi][ni] = __builtin_amdgcn_mfma_f32_16x16x32_bf16(
              af[mi][kk], bfv[ni][kk], acc[mi][ni], 0, 0, 0);
    __builtin_amdgcn_s_setprio(0);
  }
#pragma unroll
  for (int mi = 0; mi < 2; ++mi)
#pragma unroll
    for (int ni = 0; ni < 4; ++ni)
#pragma unroll
      for (int r = 0; r < 4; ++r) {
        int m = m0 + wm + mi * 16 + lg * 4 + r;
        int n = n0 + ni * 16 + lr;
        Cv[(size_t)m * N + n] = acc[mi][ni][r];
      }
}

__global__ __launch_bounds__(256) void gemm_o(
    const u16* __restrict__ Ob, const u16* __restrict__ Wob, float* __restrict__ C) {
  __shared__ __align__(16) u16 As[128 * 64];
  __shared__ __align__(16) u16 Bs[64 * 64];
  const int xcd = blockIdx.x & 7, r = blockIdx.x >> 3;
  const int mblk = xcd * 4 + (r & 3), nblk = r >> 2;
  gemm64_body(Ob, Wob, C, 1024, 1024, mblk * 128, nblk * 64, As, Bs);
}

// ---------------------------------------------------------------------------
// Flash attention v12 (proven): K-split x3, tile ranges {0..10,10..21,21..32},
// additive partials (no max-tracking), 32x32 swapped QK^T + permlane32_swap,
// row-sums via ones-MFMA, double-buffered LDS. grid = 1536, 256 thr.
// ---------------------------------------------------------------------------
__global__ __launch_bounds__(256, 4) void flash12(const u16* __restrict__ Q,
                                                  const u16* __restrict__ K,
                                                  const u16* __restrict__ VT,
                                                  const u64* __restrict__ mpk,
                                                  u16* __restrict__ O0,
                                                  u16* __restrict__ O1,
                                                  u16* __restrict__ O2,
                                                  float* __restrict__ Lp) {
  __shared__ __align__(16) u16 Ks[2][4096];   // [64 key][64 d], swizzled
  __shared__ __align__(16) u16 Vs[2][4096];   // [64 d][64 key], swizzled
  const int tid = threadIdx.x, lane = tid & 63, w = tid >> 6;
  const int c = lane & 31, h = lane >> 5;
  const int bid = blockIdx.x;
  const int xcd = bid & 7, idx = bid >> 3;        // idx 0..191
  const int gl = idx >> 4, qblk = idx & 15;       // gl 0..11
  const int group = xcd * 12 + gl;                // 0..95
  const int split = group % 3;
  const int hb = group / 3;                       // 0..31
  const int head = hb & 15, b = hb >> 4;
  const int qw = qblk * 128 + w * 32;
  const int kt0 = (split * 32) / 3;               // 0, 10, 21
  const int ktn = ((split + 1) * 32) / 3;         // 10, 21, 32
  const int nt = ktn - kt0;
  const size_t kbase = (size_t)b * 2048 * 1024 + (size_t)head * 64;
  const size_t vbase = (size_t)head * 64 * 4096 + (size_t)b * 2048;
  const int srow = lane >> 3;
  const int selem = (((lane & 7) ^ srow) << 3);
  const int rswc = (c & 7) << 3;

  bf16x8 qf[4];
#pragma unroll
  for (int kd = 0; kd < 4; ++kd)
    qf[kd] = *(const bf16x8*)&Q[kbase + (size_t)(qw + c) * 1024 + 16 * kd + 8 * h];

  union { u32 u[4]; bf16x8 v; } ones;
#pragma unroll
  for (int i = 0; i < 4; ++i) ones.u[i] = 0x3f803f80u;

  f32x16 accO0, accO1, accL;
#pragma unroll
  for (int i = 0; i < 16; ++i) { accO0[i] = 0.f; accO1[i] = 0.f; accL[i] = 0.f; }

  const u64* mrp = mpk + ((size_t)b * 2048 + qw + c) * 32;

#define STAGE(buf, t)                                                          \
  do {                                                                         \
    const int k0_ = (t) * 64;                                                  \
    _Pragma("unroll")                                                          \
    for (int r_ = 0; r_ < 2; ++r_) {                                           \
      const int c_ = w * 2 + r_;                                               \
      const int row_ = c_ * 8 + srow;                                          \
      glds16(K + kbase + (size_t)(k0_ + row_) * 1024 + selem, &Ks[buf][c_ * 512]); \
    }                                                                          \
    _Pragma("unroll")                                                          \
    for (int r_ = 0; r_ < 2; ++r_) {                                           \
      const int c_ = w * 2 + r_;                                               \
      const int row_ = c_ * 8 + srow;                                          \
      glds16(VT + vbase + (size_t)row_ * 4096 + k0_ + selem, &Vs[buf][c_ * 512]); \
    }                                                                          \
  } while (0)

  STAGE(0, kt0);
  u64 mb_next = mrp[kt0];
  __syncthreads();

  int cur = 0;
  for (int t = 0; t < nt; ++t) {
    const u64 mb = mb_next;
    if (t + 1 < nt) {
      STAGE(cur ^ 1, kt0 + t + 1);
      mb_next = mrp[kt0 + t + 1];
    }
    const u16* ks = Ks[cur];
    const u16* vs = Vs[cur];
    f32x16 s0, s1;
#pragma unroll
    for (int i = 0; i < 16; ++i) { s0[i] = 0.f; s1[i] = 0.f; }
    __builtin_amdgcn_s_setprio(1);
#pragma unroll
    for (int kd = 0; kd < 4; ++kd) {
      bf16x8 kf0 = *(bf16x8*)&ks[c * 64 + ((16 * kd + 8 * h) ^ rswc)];
      s0 = __builtin_amdgcn_mfma_f32_32x32x16_bf16(kf0, qf[kd], s0, 0, 0, 0);
      bf16x8 kf1 = *(bf16x8*)&ks[(32 + c) * 64 + ((16 * kd + 8 * h) ^ rswc)];
      s1 = __builtin_amdgcn_mfma_f32_32x32x16_bf16(kf1, qf[kd], s1, 0, 0, 0);
    }
    __builtin_amdgcn_s_setprio(0);
    u32 pw[2][4][2];
#pragma unroll
    for (int kb = 0; kb < 2; ++kb) {
      const u32 m32 = (u32)(mb >> (32 * kb + 4 * h));
      float pp[16];
#pragma unroll
      for (int g = 0; g < 4; ++g)
#pragma unroll
        for (int r = 0; r < 4; ++r) {
          float e = fexp2(kb == 0 ? s0[4 * g + r] : s1[4 * g + r]);
          pp[4 * g + r] = ((m32 >> (8 * g + r)) & 1) ? 0.0f : e;
        }
#pragma unroll
      for (int g = 0; g < 4; ++g)
#pragma unroll
        for (int hh = 0; hh < 2; ++hh)
          pw[kb][g][hh] = cvtpk(pp[4 * g + 2 * hh], pp[4 * g + 2 * hh + 1]);
    }
    __builtin_amdgcn_s_setprio(1);
#pragma unroll
    for (int kb = 0; kb < 2; ++kb)
#pragma unroll
      for (int s = 0; s < 2; ++s) {
        u32 w0 = pw[kb][2 * s][0], w2 = pw[kb][2 * s + 1][0];
        swap32(w0, w2);
        u32 w1 = pw[kb][2 * s][1], w3 = pw[kb][2 * s + 1][1];
        swap32(w1, w3);
        union { u32 u[4]; bf16x8 v; } af;
        af.u[0] = w0; af.u[1] = w1; af.u[2] = w2; af.u[3] = w3;
        const int ksg = kb * 2 + s;
        bf16x8 vf0 = *(bf16x8*)&vs[c * 64 + ((16 * ksg + 8 * h) ^ rswc)];
        accO0 = __builtin_amdgcn_mfma_f32_32x32x16_bf16(af.v, vf0, accO0, 0, 0, 0);
        bf16x8 vf1 = *(bf16x8*)&vs[(32 + c) * 64 + ((16 * ksg + 8 * h) ^ rswc)];
        accO1 = __builtin_amdgcn_mfma_f32_32x32x16_bf16(af.v, vf1, accO1, 0, 0, 0);
        accL  = __builtin_amdgcn_mfma_f32_32x32x16_bf16(af.v, ones.v, accL, 0, 0, 0);
      }
    __builtin_amdgcn_s_setprio(0);
    __syncthreads();
    cur ^= 1;
  }
#undef STAGE
  u16* Op = split == 0 ? O0 : split == 1 ? O1 : O2;
  const size_t obase = (size_t)b * 2048 + qw;
#pragma unroll
  for (int g = 0; g < 4; ++g)
#pragma unroll
    for (int r = 0; r < 4; ++r) {
      const int qrow = r + 8 * g + 4 * h;
      const size_t row = obase + qrow;
      const size_t base = row * 1024 + (size_t)head * 64 + c;
      Op[base]      = f2b(accO0[4 * g + r]);
      Op[base + 32] = f2b(accO1[4 * g + r]);
      if (c == 0) Lp[(size_t)split * 65536 + row * 16 + head] = accL[4 * g + r];
    }
}

// ---------------------------------------------------------------------------
// Combine 3 K-split partials: O = (O0+O1+O2) / (L0+L1+L2), bf16 out
// ---------------------------------------------------------------------------
__global__ __launch_bounds__(256) void combine(const u16* __restrict__ O0,
                                               const u16* __restrict__ O1,
                                               const u16* __restrict__ O2,
                                               const float* __restrict__ Lp,
                                               u16* __restrict__ Ob) {
  int gid = blockIdx.x * 256 + threadIdx.x;
  int row = gid >> 7, chb = (gid & 127) * 8;
  int head = chb >> 6;
  float l = Lp[(size_t)row * 16 + head] + Lp[65536 + (size_t)row * 16 + head] +
            Lp[131072 + (size_t)row * 16 + head];
  float inv = 1.0f / l;
  size_t off = (size_t)row * 1024 + chb;
  union { uint4 q; u16 s[8]; } a, b, c2, o;
  a.q  = *(const uint4*)(O0 + off);
  b.q  = *(const uint4*)(O1 + off);
  c2.q = *(const uint4*)(O2 + off);
#pragma unroll
  for (int j = 0; j < 8; ++j)
    o.s[j] = f2b((b2f(a.s[j]) + b2f(b.s[j]) + b2f(c2.s[j])) * inv);
  *(uint4*)(Ob + off) = o.q;
}

// ---------------------------------------------------------------------------
extern "C" void kernel_launch(void* const* d_in, const int* in_sizes, int n_in,
                              void* d_out, int out_size, void* d_ws, size_t ws_size,
                              hipStream_t stream) {
  const float* q    = (const float*)d_in[0];
  const float* k    = (const float*)d_in[1];
  const float* v    = (const float*)d_in[2];
  const u8*    mask = (const u8*)d_in[3];
  const float* Wq   = (const float*)d_in[4];
  const float* Wk   = (const float*)d_in[5];
  const float* Wv   = (const float*)d_in[6];
  const float* Wo   = (const float*)d_in[7];

  u8* ws = (u8*)d_ws;
  int* flag = (int*)ws;                         // 256 B
  u64* mpk  = (u64*)(ws + 256);                 // 1 MB
  u16* Wqb  = (u16*)(ws + 256 + (1u << 20));    // 2 MB each
  u16* Wkb  = Wqb + (1 << 20);
  u16* Wvb  = Wkb + (1 << 20);
  u16* Wob  = Wvb + (1 << 20);
  const size_t NE = (size_t)4096 * 1024;
  u16* vb   = Wob + (1 << 20);                  // 8 MB bf16 v acts; dead after qkv
  u16* O2   = vb;                               // split-2 partial reuses vb
  u16* Qb   = vb + NE;                          // 8 MB each
  u16* Kb   = Qb + NE;
  u16* VTb  = Kb + NE;                          // ws total ~41.3 MB
  u16* qb   = (u16*)d_out;                      // d_out as 16MB scratch
  u16* kb   = qb + NE;
  u16* O0   = qb;                               // partials 0,1 overwrite qb/kb
  u16* O1   = kb;
  float* Lp = (float*)Wqb;                      // 768 KB; Wqb dead after gemm_qkv
  u16* Ob   = Qb;                               // combined out reuses Qb

  const float LOG2E = 1.4426950408889634f;

  hipMemsetAsync(flag, 0, 8, stream);
  mask_detect<<<32, 256, 0, stream>>>(mask, flag);
  mask_bits<<<4096, 256, 0, stream>>>(mask, mpk, flag);
  conv_all<<<8192, 256, 0, stream>>>(Wq, Wk, Wv, Wo, q, k, v,
                                     Wqb, Wkb, Wvb, Wob, qb, kb, vb);

  gemm_qkv<<<dim3(256, 1, 3), 256, 0, stream>>>(
      qb, kb, vb, Wqb, Wkb, Wvb, Qb, Kb, VTb, 0.125f * LOG2E);

  flash12<<<1536, 256, 0, stream>>>(Qb, Kb, VTb, mpk, O0, O1, O2, Lp);
  combine<<<2048, 256, 0, stream>>>(O0, O1, O2, Lp, Ob);

  gemm_o<<<512, 256, 0, stream>>>(Ob, Wob, (float*)d_out);
}

// Round 18
// 140.895 us; speedup vs baseline: 1.2088x; 1.0126x over previous
//
#include <hip/hip_runtime.h>

typedef unsigned short u16;
typedef unsigned int   u32;
typedef unsigned char  u8;
typedef unsigned long long u64;
typedef __attribute__((ext_vector_type(8))) short bf16x8;
typedef __attribute__((ext_vector_type(4))) float f32x4;
typedef __attribute__((ext_vector_type(16))) float f32x16;

// fp32 -> bf16 (round-nearest-even), bit trick
__device__ __forceinline__ u16 f2b(float f) {
  union { float f; u32 u; } v; v.f = f;
  u32 u = v.u;
  return (u16)((u + 0x7fffu + ((u >> 16) & 1u)) >> 16);
}
__device__ __forceinline__ float b2f(u16 x) {
  union { u32 u; float f; } v; v.u = ((u32)x) << 16; return v.f;
}
__device__ __forceinline__ u32 pk2(u16 lo, u16 hi) { return (u32)lo | ((u32)hi << 16); }

// 2^x via v_exp_f32
__device__ __forceinline__ float fexp2(float x) { return __builtin_amdgcn_exp2f(x); }

// pack 2 f32 -> 2 bf16 in one instruction (RNE)
__device__ __forceinline__ u32 cvtpk(float lo, float hi) {
  u32 r;
  asm("v_cvt_pk_bf16_f32 %0, %1, %2" : "=v"(r) : "v"(lo), "v"(hi));
  return r;
}

// v_permlane32_swap_b32: a.hi32lanes <-> b.lo32lanes
__device__ __forceinline__ void swap32(u32& a, u32& b) {
  asm("v_permlane32_swap_b32 %0, %1" : "+v"(a), "+v"(b));
}

// async global->LDS, 16B per lane; LDS dest = wave-uniform base + lane*16
__device__ __forceinline__ void glds16(const u16* g, u16* l) {
  __builtin_amdgcn_global_load_lds((const __attribute__((address_space(1))) void*)g,
                                   (__attribute__((address_space(3))) void*)l, 16, 0, 0);
}

// ---------------------------------------------------------------------------
// Mask dtype detection (parallel): flag[0]!=0 -> bool; else flag[1]!=0 -> f32
// ---------------------------------------------------------------------------
__global__ __launch_bounds__(256) void mask_detect(const u8* __restrict__ raw,
                                                   int* __restrict__ flag) {
  int i = blockIdx.x * 256 + threadIdx.x;
  uint4 x = ((const uint4*)raw)[i];
  u32 o = x.x | x.y | x.z | x.w;
  u64 b1 = __ballot((o & 0x0000ff00u) != 0);
  u64 b2 = __ballot((o & 0xffff0000u) != 0);
  if ((threadIdx.x & 63) == 0) {
    if (b1) atomicOr(&flag[0], 1);
    if (b2) atomicOr(&flag[1], 1);
  }
}

// Bitpack mask, vectorized: thread t packs elements 8t..8t+7 into byte t.
__global__ __launch_bounds__(256) void mask_bits(const u8* __restrict__ raw,
                                                 u64* __restrict__ out,
                                                 const int* __restrict__ flag) {
  int f = flag[0] ? 2 : (flag[1] ? 1 : 0);
  int t = blockIdx.x * 256 + threadIdx.x;   // 4096 blocks x 256 = 1M threads
  u8 byte;
  if (f == 2) {
    u64 x = ((const u64*)raw)[t];
    u64 nz = x | (x >> 4); nz |= nz >> 2; nz |= nz >> 1;
    nz &= 0x0101010101010101ull;
    byte = (u8)((nz * 0x0102040810204080ull) >> 56);
  } else if (f == 0) {
    const int* ip = (const int*)raw + t * 8;
    int4 a = *(const int4*)ip, b = *(const int4*)(ip + 4);
    byte = (u8)((a.x != 0) | ((a.y != 0) << 1) | ((a.z != 0) << 2) | ((a.w != 0) << 3) |
                ((b.x != 0) << 4) | ((b.y != 0) << 5) | ((b.z != 0) << 6) | ((b.w != 0) << 7));
  } else {
    const float* fp = (const float*)raw + t * 8;
    float4 a = *(const float4*)fp, b = *(const float4*)(fp + 4);
    byte = (u8)((a.x != 0.f) | ((a.y != 0.f) << 1) | ((a.z != 0.f) << 2) | ((a.w != 0.f) << 3) |
                ((b.x != 0.f) << 4) | ((b.y != 0.f) << 5) | ((b.z != 0.f) << 6) | ((b.w != 0.f) << 7));
  }
  ((u8*)out)[t] = byte;
}

// ---------------------------------------------------------------------------
// Fused fp32->bf16 conversion: 4 weights (1M elems each) + 3 acts (4M each)
// ---------------------------------------------------------------------------
__global__ __launch_bounds__(256) void conv_all(
    const float* __restrict__ W0, const float* __restrict__ W1,
    const float* __restrict__ W2, const float* __restrict__ W3,
    const float* __restrict__ A0, const float* __restrict__ A1,
    const float* __restrict__ A2,
    u16* __restrict__ o0, u16* __restrict__ o1, u16* __restrict__ o2,
    u16* __restrict__ o3, u16* __restrict__ o4, u16* __restrict__ o5,
    u16* __restrict__ o6) {
  int gid = blockIdx.x * 256 + threadIdx.x;
  const float* src; u16* dst; int off;
  if (gid < 524288) {
    int wz = gid >> 17; off = (gid & 131071) * 8;
    src = wz == 0 ? W0 : wz == 1 ? W1 : wz == 2 ? W2 : W3;
    dst = wz == 0 ? o0 : wz == 1 ? o1 : wz == 2 ? o2 : o3;
  } else {
    int g2 = gid - 524288;
    int az = g2 >> 19; off = (g2 & 524287) * 8;
    src = az == 0 ? A0 : az == 1 ? A1 : A2;
    dst = az == 0 ? o4 : az == 1 ? o5 : o6;
  }
  float4 a = *(const float4*)(src + off), b2 = *(const float4*)(src + off + 4);
  uint4 t;
  t.x = pk2(f2b(a.x), f2b(a.y));   t.y = pk2(f2b(a.z), f2b(a.w));
  t.z = pk2(f2b(b2.x), f2b(b2.y)); t.w = pk2(f2b(b2.z), f2b(b2.w));
  *(uint4*)(dst + off) = t;
}

// ---------------------------------------------------------------------------
// NT GEMM body, 128x128 tile, all-bf16 glds16 staging, T2 swizzle.
// DBUF=0: single-buffered LDS (32 KB -> 5 blocks/CU), 2 barriers/K-step.
// ---------------------------------------------------------------------------
template<int CF32, int DBUF>
__device__ __forceinline__ void gemm_body(
    const u16* __restrict__ Av, const u16* __restrict__ Bv, void* __restrict__ Cv,
    int N, int K, int m0, int n0, float cscale, u16* As, u16* Bs) {
  const int tid = threadIdx.x;
  const int lane = tid & 63, w = tid >> 6;
  const int lr = lane & 15, lg = lane >> 4;
  const int wm = (w >> 1) * 64, wn = (w & 1) * 64;
  const int srow = lane >> 3;
  const int selem = (((lane & 7) ^ srow) << 3);
  const int rsw = (lr & 7) << 3;

  f32x4 acc[4][4];
#pragma unroll
  for (int mi = 0; mi < 4; ++mi)
#pragma unroll
    for (int ni = 0; ni < 4; ++ni)
      acc[mi][ni] = (f32x4){0.f, 0.f, 0.f, 0.f};

#define GLDS2(k0_, LA, LB)                                                     \
  do {                                                                         \
    _Pragma("unroll")                                                          \
    for (int r_ = 0; r_ < 4; ++r_) {                                           \
      const int c_ = w * 4 + r_;                                               \
      const int row_ = c_ * 8 + srow;                                          \
      glds16(Av + (size_t)(m0 + row_) * K + (k0_) + selem, (LA) + c_ * 512);   \
      glds16(Bv + (size_t)(n0 + row_) * K + (k0_) + selem, (LB) + c_ * 512);   \
    }                                                                          \
  } while (0)

#define FRAG_MFMA(bufA, bufB)                                                  \
  do {                                                                         \
    bf16x8 af[4][2], bfv[4][2];                                                \
    _Pragma("unroll")                                                          \
    for (int mi = 0; mi < 4; ++mi)                                             \
      _Pragma("unroll")                                                        \
      for (int kk = 0; kk < 2; ++kk)                                           \
        af[mi][kk] = *(bf16x8*)&(bufA)[(wm + mi * 16 + lr) * 64 + ((kk * 32 + lg * 8) ^ rsw)]; \
    _Pragma("unroll")                                                          \
    for (int ni = 0; ni < 4; ++ni)                                             \
      _Pragma("unroll")                                                        \
      for (int kk = 0; kk < 2; ++kk)                                           \
        bfv[ni][kk] = *(bf16x8*)&(bufB)[(wn + ni * 16 + lr) * 64 + ((kk * 32 + lg * 8) ^ rsw)]; \
    __builtin_amdgcn_s_setprio(1);                                             \
    _Pragma("unroll")                                                          \
    for (int mi = 0; mi < 4; ++mi)                                             \
      _Pragma("unroll")                                                        \
      for (int ni = 0; ni < 4; ++ni)                                           \
        _Pragma("unroll")                                                      \
        for (int kk = 0; kk < 2; ++kk)                                         \
          acc[mi][ni] = __builtin_amdgcn_mfma_f32_16x16x32_bf16(               \
              af[mi][kk], bfv[ni][kk], acc[mi][ni], 0, 0, 0);                  \
    __builtin_amdgcn_s_setprio(0);                                             \
  } while (0)

  if (DBUF) {
    GLDS2(0, As, Bs);
    __syncthreads();
    int cur = 0;
    for (int k0 = 0; k0 < K; k0 += 64) {
      if (k0 + 64 < K) GLDS2(k0 + 64, As + (cur ^ 1) * 8192, Bs + (cur ^ 1) * 8192);
      FRAG_MFMA(As + cur * 8192, Bs + cur * 8192);
      __syncthreads();
      cur ^= 1;
    }
  } else {
    for (int k0 = 0; k0 < K; k0 += 64) {
      __syncthreads();        // all waves done reading the previous tile
      GLDS2(k0, As, Bs);
      __syncthreads();        // staging drained (vmcnt0)
      FRAG_MFMA(As, Bs);
    }
  }
#undef GLDS2
#undef FRAG_MFMA
#pragma unroll
  for (int mi = 0; mi < 4; ++mi)
#pragma unroll
    for (int ni = 0; ni < 4; ++ni)
#pragma unroll
      for (int r = 0; r < 4; ++r) {
        int m = m0 + wm + mi * 16 + lg * 4 + r;
        int n = n0 + wn + ni * 16 + lr;
        float vv = acc[mi][ni][r] * cscale;
        if (CF32) ((float*)Cv)[(size_t)m * N + n] = vv;
        else      ((u16*)Cv)[(size_t)m * N + n] = f2b(vv);
      }
}

// Fused Q,K,V projections, all-bf16 (pre-converted acts), m97 single-buffer.
// XCD-swizzled. z=0 Q (scaled), z=1 K, z=2 V-transposed. grid (256,1,3).
__global__ __launch_bounds__(256) void gemm_qkv(
    const u16* __restrict__ qb, const u16* __restrict__ kb, const u16* __restrict__ vb,
    const u16* __restrict__ Wqb, const u16* __restrict__ Wkb, const u16* __restrict__ Wvb,
    u16* __restrict__ Qb, u16* __restrict__ Kb, u16* __restrict__ VTb, float qscale) {
  __shared__ __align__(16) u16 As[8192];
  __shared__ __align__(16) u16 Bs[8192];
  const int z = blockIdx.z;
  const int xcd = blockIdx.x & 7, r = blockIdx.x >> 3;   // bijective: 8*4*8=256
  const int pblk = xcd * 4 + (r & 3);                    // act panel 0..31
  const int oblk = r >> 2;                               // 0..7
  if (z < 2) {
    const u16* act = z ? kb : qb;
    const u16* Wb = z ? Wkb : Wqb;
    u16* Cb = z ? Kb : Qb;
    gemm_body<0, 0>(act, Wb, Cb, 1024, 1024, pblk * 128, oblk * 128,
                    z ? 1.0f : qscale, As, Bs);
  } else {
    gemm_body<0, 0>(Wvb, vb, VTb, 4096, 1024, oblk * 128, pblk * 128, 1.0f, As, Bs);
  }
}

// ---------------------------------------------------------------------------
// Output projection -> fp32, 128x64 tiles, XCD-swizzled, single-buffer 24 KB.
// ---------------------------------------------------------------------------
__device__ __forceinline__ void gemm64_body(
    const u16* __restrict__ Av, const u16* __restrict__ Bv, float* __restrict__ Cv,
    int N, int K, int m0, int n0, u16* As, u16* Bs) {
  const int tid = threadIdx.x;
  const int lane = tid & 63, w = tid >> 6;
  const int lr = lane & 15, lg = lane >> 4;
  const int wm = w * 32;
  const int srow = lane >> 3;
  const int selem = (((lane & 7) ^ srow) << 3);
  const int rsw = (lr & 7) << 3;

  f32x4 acc[2][4];
#pragma unroll
  for (int mi = 0; mi < 2; ++mi)
#pragma unroll
    for (int ni = 0; ni < 4; ++ni)
      acc[mi][ni] = (f32x4){0.f, 0.f, 0.f, 0.f};

  for (int k0 = 0; k0 < K; k0 += 64) {
    __syncthreads();
#pragma unroll
    for (int r_ = 0; r_ < 4; ++r_) {
      const int c_ = w * 4 + r_;
      const int row_ = c_ * 8 + srow;
      glds16(Av + (size_t)(m0 + row_) * K + k0 + selem, As + c_ * 512);
    }
#pragma unroll
    for (int r_ = 0; r_ < 2; ++r_) {
      const int c_ = w * 2 + r_;
      const int row_ = c_ * 8 + srow;
      glds16(Bv + (size_t)(n0 + row_) * K + k0 + selem, Bs + c_ * 512);
    }
    __syncthreads();
    bf16x8 af[2][2], bfv[4][2];
#pragma unroll
    for (int mi = 0; mi < 2; ++mi)
#pragma unroll
      for (int kk = 0; kk < 2; ++kk)
        af[mi][kk] = *(bf16x8*)&As[(wm + mi * 16 + lr) * 64 + ((kk * 32 + lg * 8) ^ rsw)];
#pragma unroll
    for (int ni = 0; ni < 4; ++ni)
#pragma unroll
      for (int kk = 0; kk < 2; ++kk)
        bfv[ni][kk] = *(bf16x8*)&Bs[(ni * 16 + lr) * 64 + ((kk * 32 + lg * 8) ^ rsw)];
    __builtin_amdgcn_s_setprio(1);
#pragma unroll
    for (int mi = 0; mi < 2; ++mi)
#pragma unroll
      for (int ni = 0; ni < 4; ++ni)
#pragma unroll
        for (int kk = 0; kk < 2; ++kk)
          acc[mi][ni] = __builtin_amdgcn_mfma_f32_16x16x32_bf16(
              af[mi][kk], bfv[ni][kk], acc[mi][ni], 0, 0, 0);
    __builtin_amdgcn_s_setprio(0);
  }
#pragma unroll
  for (int mi = 0; mi < 2; ++mi)
#pragma unroll
    for (int ni = 0; ni < 4; ++ni)
#pragma unroll
      for (int r = 0; r < 4; ++r) {
        int m = m0 + wm + mi * 16 + lg * 4 + r;
        int n = n0 + ni * 16 + lr;
        Cv[(size_t)m * N + n] = acc[mi][ni][r];
      }
}

__global__ __launch_bounds__(256) void gemm_o(
    const u16* __restrict__ Ob, const u16* __restrict__ Wob, float* __restrict__ C) {
  __shared__ __align__(16) u16 As[128 * 64];
  __shared__ __align__(16) u16 Bs[64 * 64];
  const int xcd = blockIdx.x & 7, r = blockIdx.x >> 3;
  const int mblk = xcd * 4 + (r & 3), nblk = r >> 2;
  gemm64_body(Ob, Wob, C, 1024, 1024, mblk * 128, nblk * 64, As, Bs);
}

// ---------------------------------------------------------------------------
// Flash attention v13: SINGLE-buffer LDS (16 KB -> 6 blocks/CU co-resident,
// m97 2-barrier loop; stage latency covered by block TLP). K-split x3 with
// corrected tile ranges {0..10,10..21,21..32}, additive partials (no max
// tracking), 32x32 swapped QK^T + permlane32_swap, row-sums via ones-MFMA.
// grid = 1536, 256 thr.
// ---------------------------------------------------------------------------
__global__ __launch_bounds__(256, 4) void flash13(const u16* __restrict__ Q,
                                                  const u16* __restrict__ K,
                                                  const u16* __restrict__ VT,
                                                  const u64* __restrict__ mpk,
                                                  u16* __restrict__ O0,
                                                  u16* __restrict__ O1,
                                                  u16* __restrict__ O2,
                                                  float* __restrict__ Lp) {
  __shared__ __align__(16) u16 Ks[4096];   // [64 key][64 d], swizzled
  __shared__ __align__(16) u16 Vs[4096];   // [64 d][64 key], swizzled
  const int tid = threadIdx.x, lane = tid & 63, w = tid >> 6;
  const int c = lane & 31, h = lane >> 5;
  const int bid = blockIdx.x;
  const int xcd = bid & 7, idx = bid >> 3;        // idx 0..191
  const int gl = idx >> 4, qblk = idx & 15;       // gl 0..11
  const int group = xcd * 12 + gl;                // 0..95
  const int split = group % 3;
  const int hb = group / 3;                       // 0..31
  const int head = hb & 15, b = hb >> 4;
  const int qw = qblk * 128 + w * 32;
  const int kt0 = (split * 32) / 3;               // 0, 10, 21
  const int ktn = ((split + 1) * 32) / 3;         // 10, 21, 32
  const int nt = ktn - kt0;
  const size_t kbase = (size_t)b * 2048 * 1024 + (size_t)head * 64;
  const size_t vbase = (size_t)head * 64 * 4096 + (size_t)b * 2048;
  const int srow = lane >> 3;
  const int selem = (((lane & 7) ^ srow) << 3);
  const int rswc = (c & 7) << 3;

  bf16x8 qf[4];
#pragma unroll
  for (int kd = 0; kd < 4; ++kd)
    qf[kd] = *(const bf16x8*)&Q[kbase + (size_t)(qw + c) * 1024 + 16 * kd + 8 * h];

  union { u32 u[4]; bf16x8 v; } ones;
#pragma unroll
  for (int i = 0; i < 4; ++i) ones.u[i] = 0x3f803f80u;

  f32x16 accO0, accO1, accL;
#pragma unroll
  for (int i = 0; i < 16; ++i) { accO0[i] = 0.f; accO1[i] = 0.f; accL[i] = 0.f; }

  const u64* mrp = mpk + ((size_t)b * 2048 + qw + c) * 32;

  for (int t = 0; t < nt; ++t) {
    __syncthreads();   // all waves done reading the previous tile (no-op @ t=0)
    // stage tile kt0+t into the single buffer
    {
      const int k0_ = (kt0 + t) * 64;
#pragma unroll
      for (int r_ = 0; r_ < 2; ++r_) {
        const int c_ = w * 2 + r_;
        const int row_ = c_ * 8 + srow;
        glds16(K + kbase + (size_t)(k0_ + row_) * 1024 + selem, &Ks[c_ * 512]);
      }
#pragma unroll
      for (int r_ = 0; r_ < 2; ++r_) {
        const int c_ = w * 2 + r_;
        const int row_ = c_ * 8 + srow;
        glds16(VT + vbase + (size_t)row_ * 4096 + k0_ + selem, &Vs[c_ * 512]);
      }
    }
    const u64 mb = mrp[kt0 + t];
    __syncthreads();   // staging drained (vmcnt0 + lgkmcnt0)
    // swapped QK^T (32x32x16): lane holds P[q=c][key=(reg&3)+8*(reg>>2)+4h+32kb]
    f32x16 s0, s1;
#pragma unroll
    for (int i = 0; i < 16; ++i) { s0[i] = 0.f; s1[i] = 0.f; }
    __builtin_amdgcn_s_setprio(1);
#pragma unroll
    for (int kd = 0; kd < 4; ++kd) {
      bf16x8 kf0 = *(bf16x8*)&Ks[c * 64 + ((16 * kd + 8 * h) ^ rswc)];
      s0 = __builtin_amdgcn_mfma_f32_32x32x16_bf16(kf0, qf[kd], s0, 0, 0, 0);
      bf16x8 kf1 = *(bf16x8*)&Ks[(32 + c) * 64 + ((16 * kd + 8 * h) ^ rswc)];
      s1 = __builtin_amdgcn_mfma_f32_32x32x16_bf16(kf1, qf[kd], s1, 0, 0, 0);
    }
    __builtin_amdgcn_s_setprio(0);
    // mask + exp2 (no max-subtraction: scores bounded); pack to bf16
    u32 pw[2][4][2];
#pragma unroll
    for (int kb = 0; kb < 2; ++kb) {
      const u32 m32 = (u32)(mb >> (32 * kb + 4 * h));
      float pp[16];
#pragma unroll
      for (int g = 0; g < 4; ++g)
#pragma unroll
        for (int r = 0; r < 4; ++r) {
          float e = fexp2(kb == 0 ? s0[4 * g + r] : s1[4 * g + r]);
          pp[4 * g + r] = ((m32 >> (8 * g + r)) & 1) ? 0.0f : e;
        }
#pragma unroll
      for (int g = 0; g < 4; ++g)
#pragma unroll
        for (int hh = 0; hh < 2; ++hh)
          pw[kb][g][hh] = cvtpk(pp[4 * g + 2 * hh], pp[4 * g + 2 * hh + 1]);
    }
    // PV + row-sum MFMA: A-frag via one permlane32_swap per word-pair
    __builtin_amdgcn_s_setprio(1);
#pragma unroll
    for (int kb = 0; kb < 2; ++kb)
#pragma unroll
      for (int s = 0; s < 2; ++s) {
        u32 w0 = pw[kb][2 * s][0], w2 = pw[kb][2 * s + 1][0];
        swap32(w0, w2);
        u32 w1 = pw[kb][2 * s][1], w3 = pw[kb][2 * s + 1][1];
        swap32(w1, w3);
        union { u32 u[4]; bf16x8 v; } af;
        af.u[0] = w0; af.u[1] = w1; af.u[2] = w2; af.u[3] = w3;
        const int ksg = kb * 2 + s;
        bf16x8 vf0 = *(bf16x8*)&Vs[c * 64 + ((16 * ksg + 8 * h) ^ rswc)];
        accO0 = __builtin_amdgcn_mfma_f32_32x32x16_bf16(af.v, vf0, accO0, 0, 0, 0);
        bf16x8 vf1 = *(bf16x8*)&Vs[(32 + c) * 64 + ((16 * ksg + 8 * h) ^ rswc)];
        accO1 = __builtin_amdgcn_mfma_f32_32x32x16_bf16(af.v, vf1, accO1, 0, 0, 0);
        accL  = __builtin_amdgcn_mfma_f32_32x32x16_bf16(af.v, ones.v, accL, 0, 0, 0);
      }
    __builtin_amdgcn_s_setprio(0);
  }
  // epilogue: unnormalized partials; accL[4g+r] = rowsum(qrow) on all lanes
  u16* Op = split == 0 ? O0 : split == 1 ? O1 : O2;
  const size_t obase = (size_t)b * 2048 + qw;
#pragma unroll
  for (int g = 0; g < 4; ++g)
#pragma unroll
    for (int r = 0; r < 4; ++r) {
      const int qrow = r + 8 * g + 4 * h;
      const size_t row = obase + qrow;
      const size_t base = row * 1024 + (size_t)head * 64 + c;
      Op[base]      = f2b(accO0[4 * g + r]);
      Op[base + 32] = f2b(accO1[4 * g + r]);
      if (c == 0) Lp[(size_t)split * 65536 + row * 16 + head] = accL[4 * g + r];
    }
}

// ---------------------------------------------------------------------------
// Combine 3 K-split partials: O = (O0+O1+O2) / (L0+L1+L2), bf16 out
// ---------------------------------------------------------------------------
__global__ __launch_bounds__(256) void combine(const u16* __restrict__ O0,
                                               const u16* __restrict__ O1,
                                               const u16* __restrict__ O2,
                                               const float* __restrict__ Lp,
                                               u16* __restrict__ Ob) {
  int gid = blockIdx.x * 256 + threadIdx.x;
  int row = gid >> 7, chb = (gid & 127) * 8;
  int head = chb >> 6;
  float l = Lp[(size_t)row * 16 + head] + Lp[65536 + (size_t)row * 16 + head] +
            Lp[131072 + (size_t)row * 16 + head];
  float inv = 1.0f / l;
  size_t off = (size_t)row * 1024 + chb;
  union { uint4 q; u16 s[8]; } a, b, c2, o;
  a.q  = *(const uint4*)(O0 + off);
  b.q  = *(const uint4*)(O1 + off);
  c2.q = *(const uint4*)(O2 + off);
#pragma unroll
  for (int j = 0; j < 8; ++j)
    o.s[j] = f2b((b2f(a.s[j]) + b2f(b.s[j]) + b2f(c2.s[j])) * inv);
  *(uint4*)(Ob + off) = o.q;
}

// ---------------------------------------------------------------------------
extern "C" void kernel_launch(void* const* d_in, const int* in_sizes, int n_in,
                              void* d_out, int out_size, void* d_ws, size_t ws_size,
                              hipStream_t stream) {
  const float* q    = (const float*)d_in[0];
  const float* k    = (const float*)d_in[1];
  const float* v    = (const float*)d_in[2];
  const u8*    mask = (const u8*)d_in[3];
  const float* Wq   = (const float*)d_in[4];
  const float* Wk   = (const float*)d_in[5];
  const float* Wv   = (const float*)d_in[6];
  const float* Wo   = (const float*)d_in[7];

  u8* ws = (u8*)d_ws;
  int* flag = (int*)ws;                         // 256 B
  u64* mpk  = (u64*)(ws + 256);                 // 1 MB
  u16* Wqb  = (u16*)(ws + 256 + (1u << 20));    // 2 MB each
  u16* Wkb  = Wqb + (1 << 20);
  u16* Wvb  = Wkb + (1 << 20);
  u16* Wob  = Wvb + (1 << 20);
  const size_t NE = (size_t)4096 * 1024;
  u16* vb   = Wob + (1 << 20);                  // 8 MB bf16 v acts; dead after qkv
  u16* O2   = vb;                               // split-2 partial reuses vb
  u16* Qb   = vb + NE;                          // 8 MB each
  u16* Kb   = Qb + NE;
  u16* VTb  = Kb + NE;                          // ws total ~41.3 MB
  u16* qb   = (u16*)d_out;                      // d_out as 16MB scratch
  u16* kb   = qb + NE;
  u16* O0   = qb;                               // partials 0,1 overwrite qb/kb
  u16* O1   = kb;
  float* Lp = (float*)Wqb;                      // 768 KB; Wqb dead after gemm_qkv
  u16* Ob   = Qb;                               // combined out reuses Qb

  const float LOG2E = 1.4426950408889634f;

  hipMemsetAsync(flag, 0, 8, stream);
  mask_detect<<<32, 256, 0, stream>>>(mask, flag);
  mask_bits<<<4096, 256, 0, stream>>>(mask, mpk, flag);
  conv_all<<<8192, 256, 0, stream>>>(Wq, Wk, Wv, Wo, q, k, v,
                                     Wqb, Wkb, Wvb, Wob, qb, kb, vb);

  gemm_qkv<<<dim3(256, 1, 3), 256, 0, stream>>>(
      qb, kb, vb, Wqb, Wkb, Wvb, Qb, Kb, VTb, 0.125f * LOG2E);

  flash13<<<1536, 256, 0, stream>>>(Qb, Kb, VTb, mpk, O0, O1, O2, Lp);
  combine<<<2048, 256, 0, stream>>>(O0, O1, O2, Lp, Ob);

  gemm_o<<<512, 256, 0, stream>>>(Ob, Wob, (float*)d_out);
}